// Round 8
// baseline (273.222 us; speedup 1.0000x reference)
//
#include <hip/hip_runtime.h>

// RandomlyLocalizedConformalRiskControl on MI355X.
// ws layout (bytes), total ~98.4 MB:
//   test_res f32 [32][65536]             @ 0          (8 MB)    f32 scores for final scan
//   cal_bf   u16 [256][65536]            @ 8388608    (32 MB)   bf16 cal scores (MFMA A/B)
//   test_bf  u16 [32][65536]             @ 41943040   (4 MB)    bf16 test scores
//   grouped  u16 [256][65536]            @ 46137344   (32 MB)   low-16 bits of f32 score, grouped by hi-16 bucket
//   cdf      u16 [256][CDF_STRIDE]       @ 79691776   (8.3 MB)  exclusive CDF, row-major (gather/pos)
//   gpart    f32 [64][8][1024]           @ 88023040   (2 MB)    split-K MFMA partials (deterministic)
//   cc f32[256], thr f32[32], lam f32[32], facc i32[32][4]
//   cdfT     u16 [16256][256]            @ 90122240   (8.3 MB)  TRANSPOSED cdf: coalesced binary search
// Pipeline (4 launches): k_calt -> k_gemmtr (GEMM + cdf transpose merged) -> k_quantw
// -> k_finalp (absorbs k_out).

#define NPIX 65536
#define HB 16256            // buckets = float_bits >> 16 for scores in (0, 1.0]
#define CDF_STRIDE 16272
#define ALPHA 0.1f
#define STAGE_CAP 35840     // u16 staging entries; pos ~ Bin(65536,1/2) max ~33.4K (+24 sigma)

#define OFF_TESTRES  0
#define OFF_CALBF    8388608u
#define OFF_TESTBF   41943040u
#define OFF_GROUPED  46137344u
#define OFF_CDF      79691776u
#define OFF_GPART    88023040u
#define OFF_CC       90120192u
#define OFF_THR      90121216u
#define OFF_LAM      90121344u
#define OFF_FACC     90121472u
#define OFF_CDFT     90122240u

typedef __attribute__((ext_vector_type(8))) short bf16x8;
typedef __attribute__((ext_vector_type(16))) float f32x16;

__device__ __forceinline__ unsigned f2bf_rne(float f) {
  unsigned u = __float_as_uint(f);
  return (u + 0x7FFFu + ((u >> 16) & 1u)) >> 16;
}

// XOR swizzle on bucket index: involution, closed within each 32-word block.
__device__ __forceinline__ int SW(int w) { return w ^ ((w >> 5) & 31); }

// The sigmoid tail shared by ALL score evaluation sites: identical inlined expression
// tree -> identical FMA contraction -> bit-identical f32 on every recompute/reuse.
__device__ __forceinline__ float sig_v(float a, float b, float wy) {
  float v = a * (1.f - wy) + b * wy;
  return 1.f / (1.f + __expf(-v));
}

// Row x-interp for the 4 pixels of a thread's patch: SAME source expression shape as
// the original score_at row interp (f[x0]*(1-wx) + f[x1]*wx with runtime wx), operands
// pre-selected per-k (cL/cM/cR reproduce the clamped x0/x1 pairs exactly, including
// the x=0 / x=255 both-operands-equal corner cases).
#define ROWH(F, r, h0, h1, h2, h3)                                        \
  {                                                                       \
    float fL_ = (F)[(r) * 64 + cL];                                       \
    float fM_ = (F)[(r) * 64 + cM];                                       \
    float fR_ = (F)[(r) * 64 + cR];                                       \
    h0 = fL_ * (1.f - wx0) + fM_ * wx0;                                   \
    h1 = fL_ * (1.f - wx1) + fM_ * wx1;                                   \
    h2 = fM_ * (1.f - wx2) + fR_ * wx2;                                   \
    h3 = fM_ * (1.f - wx3) + fR_ * wx3;                                   \
  }

// ---- fused cal+test features, 256 blocks (one per cal sample) ----
// R8: 4-pixel-wide patches — thread (xg, band) owns x=4xg..4xg+3, rows [16*band,+16)
// (4 quads). Per row: one sy/wy shared by 4 pixels; 3 LDS feature reads feed 4
// x-interps; stores packed (uint2 calbf/tbf, float4 tres); one gt-bitmask word read
// per 4 pixels. Per-pixel score bits identical (same expression trees, same operand
// values); cc accumulation order reassociated (accepted precedent, R6).
// smem map (u32): [0,16256) hist -> CDF -> scatter counters (swizzled); [16256,16272)
// scan wave totals; [16272,16288) cc partials; [16288,17312) thread prefixes; [17312] pos.
__global__ __launch_bounds__(1024, 2) void k_calt(const float* __restrict__ featc,
                                                  const int* __restrict__ gt,
                                                  unsigned short* __restrict__ calbf,
                                                  unsigned short* __restrict__ cdf,
                                                  unsigned short* __restrict__ grouped,
                                                  float* __restrict__ cc,
                                                  const float* __restrict__ featt,
                                                  float* __restrict__ tres,
                                                  unsigned short* __restrict__ tbf) {
  __shared__ unsigned smem[17313];
  __shared__ float sfeat[4096];
  __shared__ __align__(16) unsigned short sstage[STAGE_CAP];
  float* tfeat = (float*)sstage;                    // sstage[0..8191]: dead before phase B
  unsigned* gmask = (unsigned*)(sstage + 8192);     // sstage[8192..12287]: dead before phase B
  const int tid = threadIdx.x;
  const int lane = tid & 63, wv = tid >> 6;
  const int xg = tid & 63, band = tid >> 6;  // patch col group / 16-row band
  // per-k x-interp params: identical per-pixel computation as before (x = 4*xg + k)
  float wx0, wx1, wx2, wx3;
  {
    float sx0 = 0.25f * (float)(4 * xg + 0) - 0.375f;
    float sx1 = 0.25f * (float)(4 * xg + 1) - 0.375f;
    float sx2 = 0.25f * (float)(4 * xg + 2) - 0.375f;
    float sx3 = 0.25f * (float)(4 * xg + 3) - 0.375f;
    wx0 = sx0 - (float)((int)floorf(sx0));
    wx1 = sx1 - (float)((int)floorf(sx1));
    wx2 = sx2 - (float)((int)floorf(sx2));
    wx3 = sx3 - (float)((int)floorf(sx3));
  }
  const int cL = (xg == 0) ? 0 : xg - 1;
  const int cM = xg;
  const int cR = (xg == 63) ? 63 : xg + 1;

  const int n = blockIdx.x;
  const int b = n >> 3, sl = n & 7;  // test sample + slice handled by this block
  for (int i = tid; i < HB; i += 1024) smem[i] = 0;
  for (int i = tid; i < 4096; i += 1024) {
    sfeat[i] = featc[n * 4096 + i];
    tfeat[i] = featt[b * 4096 + i];
  }
  // gt bitmask pre-pass: coalesced int4 loads -> 8 KB LDS bitmask
  {
    const int4* gt4 = (const int4*)(gt + (size_t)n * NPIX);
    for (int w = tid; w < 2048; w += 1024) {
      unsigned m = 0;
      #pragma unroll
      for (int j = 0; j < 8; ++j) {
        int4 g = gt4[w * 8 + j];
        m |= (g.x > 0 ? 1u : 0u) << (j * 4);
        m |= (g.y > 0 ? 2u : 0u) << (j * 4);
        m |= (g.z > 0 ? 4u : 0u) << (j * 4);
        m |= (g.w > 0 ? 8u : 0u) << (j * 4);
      }
      gmask[w] = m;
    }
  }
  unsigned short* cbn = calbf + (size_t)n * NPIX;
  __syncthreads();  // S0: feats + hist + gmask ready

  // ---- test slice: rows {sl*32+2*band, +1} x cols 4xg..4xg+3 (one quad window) ----
  {
    const int tr0 = sl * 32 + 2 * band;
    const int mt = tr0 >> 2, j0 = tr0 & 3;  // quad, first row-in-quad (0 or 2)
    float tp0, tp1, tp2, tp3, tc0, tc1, tc2, tc3, tn0, tn1, tn2, tn3;
    int rp = (mt == 0) ? 0 : mt - 1;
    int rn = (mt == 63) ? 63 : mt + 1;
    ROWH(tfeat, rp, tp0, tp1, tp2, tp3);
    ROWH(tfeat, mt, tc0, tc1, tc2, tc3);
    ROWH(tfeat, rn, tn0, tn1, tn2, tn3);
    float* resb = tres + (size_t)b * NPIX;
    unsigned short* tbn = tbf + (size_t)b * NPIX;
    #pragma unroll
    for (int jj = 0; jj < 2; ++jj) {
      int j = j0 + jj;
      int y = 4 * mt + j;
      float sy = 0.25f * (float)y - 0.375f;
      int y0i = (int)floorf(sy);
      float wy = sy - (float)y0i;
      float a0 = j < 2 ? tp0 : tc0, b0 = j < 2 ? tc0 : tn0;
      float a1 = j < 2 ? tp1 : tc1, b1 = j < 2 ? tc1 : tn1;
      float a2 = j < 2 ? tp2 : tc2, b2 = j < 2 ? tc2 : tn2;
      float a3 = j < 2 ? tp3 : tc3, b3 = j < 2 ? tc3 : tn3;
      float s0 = sig_v(a0, b0, wy), s1 = sig_v(a1, b1, wy);
      float s2 = sig_v(a2, b2, wy), s3 = sig_v(a3, b3, wy);
      float4 rv = {s0, s1, s2, s3};
      *(float4*)(resb + (y << 8) + 4 * xg) = rv;
      uint2 pk;
      pk.x = f2bf_rne(s0) | (f2bf_rne(s1) << 16);
      pk.y = f2bf_rne(s2) | (f2bf_rne(s3) << 16);
      *(uint2*)(tbn + (y << 8) + 4 * xg) = pk;
    }
  }

  // ---- cal phase A: 4-wide patch scores, packed stores, bitmask, hist, cc ----
  const int mq0 = band * 4;  // quads mq0..mq0+3 (rows 16*band..+15)
  unsigned long long pm = 0ull;
  float sumsq = 0.f;
  {
    float hp0, hp1, hp2, hp3, hc0, hc1, hc2, hc3, hn0, hn1, hn2, hn3;
    int rp = (mq0 == 0) ? 0 : mq0 - 1;
    ROWH(sfeat, rp, hp0, hp1, hp2, hp3);
    ROWH(sfeat, mq0, hc0, hc1, hc2, hc3);
    for (int qq = 0; qq < 4; ++qq) {
      int m = mq0 + qq;
      int rn = (m == 63) ? 63 : m + 1;
      ROWH(sfeat, rn, hn0, hn1, hn2, hn3);
      #pragma unroll
      for (int j = 0; j < 4; ++j) {
        int y = 4 * m + j;
        float sy = 0.25f * (float)y - 0.375f;
        int y0i = (int)floorf(sy);
        float wy = sy - (float)y0i;
        float a0 = j < 2 ? hp0 : hc0, b0 = j < 2 ? hc0 : hn0;
        float a1 = j < 2 ? hp1 : hc1, b1 = j < 2 ? hc1 : hn1;
        float a2 = j < 2 ? hp2 : hc2, b2 = j < 2 ? hc2 : hn2;
        float a3 = j < 2 ? hp3 : hc3, b3 = j < 2 ? hc3 : hn3;
        float s0 = sig_v(a0, b0, wy), s1 = sig_v(a1, b1, wy);
        float s2 = sig_v(a2, b2, wy), s3 = sig_v(a3, b3, wy);
        unsigned u0 = f2bf_rne(s0), u1 = f2bf_rne(s1);
        unsigned u2 = f2bf_rne(s2), u3 = f2bf_rne(s3);
        uint2 pk;
        pk.x = u0 | (u1 << 16);
        pk.y = u2 | (u3 << 16);
        *(uint2*)(cbn + (y << 8) + 4 * xg) = pk;
        float r0 = __uint_as_float(u0 << 16), r1 = __uint_as_float(u1 << 16);
        float r2 = __uint_as_float(u2 << 16), r3 = __uint_as_float(u3 << 16);
        sumsq += r0 * r0;
        sumsq += r1 * r1;
        sumsq += r2 * r2;
        sumsq += r3 * r3;
        unsigned nib = (gmask[(y << 3) + (xg >> 3)] >> (4 * (xg & 7))) & 0xFu;
        if (nib & 1u) {
          pm |= 1ull << (qq * 16 + j * 4 + 0);
          atomicAdd(&smem[SW((int)(__float_as_uint(s0) >> 16))], 1u);
        }
        if (nib & 2u) {
          pm |= 1ull << (qq * 16 + j * 4 + 1);
          atomicAdd(&smem[SW((int)(__float_as_uint(s1) >> 16))], 1u);
        }
        if (nib & 4u) {
          pm |= 1ull << (qq * 16 + j * 4 + 2);
          atomicAdd(&smem[SW((int)(__float_as_uint(s2) >> 16))], 1u);
        }
        if (nib & 8u) {
          pm |= 1ull << (qq * 16 + j * 4 + 3);
          atomicAdd(&smem[SW((int)(__float_as_uint(s3) >> 16))], 1u);
        }
      }
      hp0 = hc0; hp1 = hc1; hp2 = hc2; hp3 = hc3;
      hc0 = hn0; hc1 = hn1; hc2 = hn2; hc3 = hn3;
    }
  }
  // cc partials (16 waves); band-patch accumulation order (reassociation accepted)
  #pragma unroll
  for (int off = 32; off; off >>= 1) sumsq += __shfl_xor(sumsq, off);
  if (lane == 0) smem[16272 + wv] = __float_as_uint(sumsq);
  __syncthreads();  // S1: hist + cc partials final
  if (tid == 0) {
    float c = 0.f;
    for (int w = 0; w < 16; ++w) c += __uint_as_float(smem[16272 + w]);
    cc[n] = c;
  }
  // ---- exclusive scan: threads 0..1015, 16 buckets each ----
  const int base = tid * 16;
  unsigned psum = 0;
  if (tid < 1016) {
    #pragma unroll
    for (int j = 0; j < 16; ++j) psum += smem[SW(base + j)];
  }
  unsigned inc = psum;
  #pragma unroll
  for (int off = 1; off < 64; off <<= 1) {
    unsigned v = __shfl_up(inc, off);
    if (lane >= off) inc += v;
  }
  if (lane == 63) smem[16256 + wv] = inc;  // wave totals
  smem[16288 + tid] = inc - psum;          // thread-exclusive prefix within wave
  __syncthreads();  // S2: totals + prefixes ready
  {
    unsigned woff = 0;
    for (int w = 0; w < wv; ++w) woff += smem[16256 + w];  // broadcast reads
    unsigned run = woff + smem[16288 + tid];
    if (tid < 1016) {
      #pragma unroll
      for (int j = 0; j < 16; ++j) {
        int si = SW(base + j);
        unsigned h = smem[si];
        smem[si] = run;  // exclusive CDF -> scatter counters
        run += h;
      }
    }
    if (tid == 1015) smem[17312] = run;  // total positives (lanes above 1015 hold 0)
  }
  __syncthreads();  // S2b: counters final
  // ---- COALESCED u16 cdf copyout ----
  unsigned short* cdfn = cdf + (size_t)n * CDF_STRIDE;
  for (int i = tid; i < HB; i += 1024) cdfn[i] = (unsigned short)smem[SW(i)];
  const unsigned pos = smem[17312];
  if (tid == 0) cdfn[HB] = (unsigned short)pos;  // pos < 2^16 for Bin(65536,1/2) data
  __syncthreads();  // S3: cdf written before counters mutate
  // ---- phase B: patch recompute (bit-exact expression reuse), LDS staging ----
  unsigned short* gn = grouped + (size_t)n * NPIX;
  {
    float hp0, hp1, hp2, hp3, hc0, hc1, hc2, hc3, hn0, hn1, hn2, hn3;
    int rp = (mq0 == 0) ? 0 : mq0 - 1;
    ROWH(sfeat, rp, hp0, hp1, hp2, hp3);
    ROWH(sfeat, mq0, hc0, hc1, hc2, hc3);
    for (int qq = 0; qq < 4; ++qq) {
      int m = mq0 + qq;
      int rn = (m == 63) ? 63 : m + 1;
      ROWH(sfeat, rn, hn0, hn1, hn2, hn3);
      unsigned qb = (unsigned)(pm >> (qq * 16)) & 0xFFFFu;
      if (qb) {
        #pragma unroll
        for (int j = 0; j < 4; ++j) {
          unsigned nib = (qb >> (j * 4)) & 0xFu;
          if (nib) {
            int y = 4 * m + j;
            float sy = 0.25f * (float)y - 0.375f;
            int y0i = (int)floorf(sy);
            float wy = sy - (float)y0i;
            float a0 = j < 2 ? hp0 : hc0, b0 = j < 2 ? hc0 : hn0;
            float a1 = j < 2 ? hp1 : hc1, b1 = j < 2 ? hc1 : hn1;
            float a2 = j < 2 ? hp2 : hc2, b2 = j < 2 ? hc2 : hn2;
            float a3 = j < 2 ? hp3 : hc3, b3 = j < 2 ? hc3 : hn3;
            #pragma unroll
            for (int k = 0; k < 4; ++k) {
              if (nib & (1u << k)) {
                float s = k == 0 ? sig_v(a0, b0, wy)
                        : k == 1 ? sig_v(a1, b1, wy)
                        : k == 2 ? sig_v(a2, b2, wy)
                                 : sig_v(a3, b3, wy);
                unsigned bits = __float_as_uint(s);
                unsigned idx = atomicAdd(&smem[SW((int)(bits >> 16))], 1u);
                unsigned short lo = (unsigned short)(bits & 0xFFFFu);
                if (idx < STAGE_CAP) sstage[idx] = lo;
                else gn[idx] = lo;  // overflow fallback: same final location
              }
            }
          }
        }
      }
      hp0 = hc0; hp1 = hc1; hp2 = hc2; hp3 = hc3;
      hc0 = hn0; hc1 = hn1; hc2 = hn2; hc3 = hn3;
    }
  }
  __syncthreads();  // S4: staging complete
  // ---- COALESCED grouped copyout ----
  unsigned lim = pos < STAGE_CAP ? pos : STAGE_CAP;
  for (unsigned i = tid; i < lim; i += 1024) gn[i] = sstage[i];
}

// ---- merged GEMM + cdf transpose (grid (8,65); y==64 row = transpose role) ----
// GEMM: gpart[ks][nt][m*32+nl] = <test_m, cal_(nt*32+nl)>, LDS-staged, XOR-swizzled,
// 32x32x16 bf16 MFMA, wave = K-quarter split, cross-wave reduce in lred.
// Transpose: cdfT[bucket][n] = cdf[n][bucket] — faithful copy, bit-exact search input.
// LDS overlay: gemm uses 80 KB (As 32 + Bs 32 + lred 16); transpose 69.6 KB tile.
__global__ __launch_bounds__(256) void k_gemmtr(const unsigned short* __restrict__ tbf,
                                                const unsigned short* __restrict__ cbf,
                                                float* __restrict__ gpart,
                                                const unsigned short* __restrict__ cdf,
                                                unsigned short* __restrict__ cdfT) {
  __shared__ __align__(16) char lds[81920];
  const int tid = threadIdx.x;
  if (blockIdx.y == 64) {
    // ---- transpose role: 8 blocks, ~16 tiles of 128 buckets each ----
    unsigned short (*tile)[136] = (unsigned short (*)[136])lds;  // 16B-aligned rows
    for (int t = blockIdx.x; t < 127; t += 8) {
      const int b0 = t * 128;
      const unsigned short* src = cdf + (size_t)tid * CDF_STRIDE + b0;
      __syncthreads();  // tile reuse guard
      #pragma unroll
      for (int j = 0; j < 128; j += 8)
        *(int4*)&tile[tid][j] = *(const int4*)(src + j);
      __syncthreads();
      for (int j = 0; j < 128; ++j)
        cdfT[(size_t)(b0 + j) * 256 + tid] = tile[tid][j];
    }
    return;
  }
  // ---- GEMM role ----
  unsigned short* As = (unsigned short*)lds;            // 32 KB
  unsigned short* Bs = (unsigned short*)(lds + 32768);  // 32 KB
  float (*lred)[1024] = (float (*)[1024])(lds + 65536); // 16 KB
  const int lane = tid & 63, wv = tid >> 6;
  const int r = lane & 31, half = lane >> 5;
  const int nt = blockIdx.x;              // 0..7: cal column tile
  f32x16 acc;
  #pragma unroll
  for (int i = 0; i < 16; ++i) acc[i] = 0.f;
  for (int ch = 0; ch < 2; ++ch) {        // two 512-K chunks of this block's 1024-K slice
    const size_t kbase = (size_t)blockIdx.y * 1024 + ch * 512;
    __syncthreads();
    #pragma unroll
    for (int s = 0; s < 16; ++s) {
      int flat = s * 256 + tid;           // 0..4095; <2048 = A, else B (wave-uniform per s)
      int rem = flat & 2047;
      int row = rem >> 6, kb = rem & 63;
      const unsigned short* src = (flat >= 2048)
          ? cbf + (size_t)(nt * 32 + row) * NPIX + kbase + kb * 8
          : tbf + (size_t)row * NPIX + kbase + kb * 8;
      int slot = ((kb << 5) + row) ^ (kb & 31);   // XOR swizzle breaks write-bank collisions
      int4 v = *(const int4*)src;
      *(int4*)((flat >= 2048 ? Bs : As) + slot * 8) = v;
    }
    __syncthreads();
    #pragma unroll
    for (int i = 0; i < 8; ++i) {         // wave's K-quarter: kblk in [wv*16, wv*16+16)
      int k8 = (wv << 4) + i * 2 + half;
      int slot = ((k8 << 5) + r) ^ (k8 & 31);
      bf16x8 a = *(const bf16x8*)(As + slot * 8);
      bf16x8 b = *(const bf16x8*)(Bs + slot * 8);
      acc = __builtin_amdgcn_mfma_f32_32x32x16_bf16(a, b, acc, 0, 0, 0);
    }
  }
  // C/D layout (HW-verified): col = lane&31, row = (reg&3) + 8*(reg>>2) + 4*(lane>>5)
  #pragma unroll
  for (int rg = 0; rg < 16; ++rg) {
    int m = (rg & 3) + 8 * (rg >> 2) + 4 * half;
    lred[wv][m * 32 + r] = acc[rg];
  }
  __syncthreads();
  float* gp = gpart + (size_t)(blockIdx.y * 8 + nt) * 1024;
  for (int e = tid; e < 1024; e += 256)
    gp[e] = lred[0][e] + lred[1][e] + lred[2][e] + lred[3][e];
}

// ---- tt + weights + weighted-quantile; zero-inits facc; writes thr/lam ----
__global__ __launch_bounds__(512) void k_quantw(const float* __restrict__ gpart,
                                                const float* __restrict__ cc,
                                                const unsigned short* __restrict__ tbf,
                                                const unsigned short* __restrict__ cdf,
                                                const unsigned short* __restrict__ cdfT,
                                                const unsigned short* __restrict__ grouped,
                                                float* __restrict__ lam,
                                                float* __restrict__ thr,
                                                int* __restrict__ facc) {
  __shared__ float qs[256];
  __shared__ float bins[4096];
  __shared__ float red[8];
  __shared__ float tpart[16];
  __shared__ float bc[3];      // [0]=wsum [1]=S(mid) [2]=tt
  __shared__ unsigned sBin;
  const int b = blockIdx.x, tid = threadIdx.x;
  const int lane = tid & 63, wv = tid >> 6;

  if (tid < 4) facc[b * 4 + tid] = 0;
  for (int i = tid; i < 4096; i += 512) bins[i] = 0.f;
  if (tid == 0) sBin = 0xFFFFFFFFu;

  // ---- tt[b]: bit-exact virtual-thread replica of the original 1024-thread reduction ----
  {
    const unsigned short* tbn = tbf + (size_t)b * NPIX;
    const int xa = tid & 255, ya = tid >> 8;        // virtual thread vt = tid
    const int yb = ya + 2;                          // virtual thread vt = tid + 512
    float sa = 0.f, sb = 0.f;
    #pragma unroll 4
    for (int it = 0; it < 64; ++it) {
      float ra = __uint_as_float((unsigned)tbn[((it * 4 + ya) << 8) + xa] << 16);
      float rb = __uint_as_float((unsigned)tbn[((it * 4 + yb) << 8) + xa] << 16);
      sa += ra * ra;
      sb += rb * rb;
    }
    #pragma unroll
    for (int off = 32; off; off >>= 1) {
      sa += __shfl_xor(sa, off);
      sb += __shfl_xor(sb, off);
    }
    if (lane == 0) { tpart[wv] = sa; tpart[8 + wv] = sb; }
  }
  __syncthreads();
  if (tid == 0) {
    float t = 0.f;
    for (int w = 0; w < 16; ++w) t += tpart[w];
    bc[2] = t;
  }
  // ---- weights g-sum (independent of tt) ----
  float g = 0.f;
  if (tid < 256) {
    const float* gp = gpart + ((tid >> 5) * 1024) + (b * 32) + (tid & 31);
    #pragma unroll 8
    for (int ks = 0; ks < 64; ++ks) g += gp[(size_t)ks * 8192];
  }
  __syncthreads();  // bc[2] visible
  float k = 0.f;
  if (tid < 256) {
    float d2 = bc[2] + cc[tid] - 2.f * g;
    k = expf(-d2 * (1.f / 8192.f));
  }
  float v = k;
  #pragma unroll
  for (int off = 32; off; off >>= 1) v += __shfl_xor(v, off);
  if (lane == 0) red[wv] = v;
  __syncthreads();
  if (tid == 0) {
    float ws = 1.f;
    for (int w = 0; w < 8; ++w) ws += red[w];
    bc[0] = ws;
  }
  __syncthreads();
  const float wsum = bc[0];
  const float wlast = 1.f / wsum;
  const float R = ALPHA - wlast;
  if (R <= 0.f) {  // risk >= alpha for every lam -> low -> 1.0f, thr 0 (predict all)
    if (tid == 0) { lam[b] = 1.0f; thr[b] = 0.0f; }
    return;
  }
  if (tid < 256) {
    unsigned pos = cdf[(size_t)tid * CDF_STRIDE + HB];
    qs[tid] = k / (wsum * (float)(pos ? pos : 1u));
  }
  __syncthreads();

  // ---- 14-step binary search over hi-16 buckets (coalesced via cdfT) ----
  int lo = 0, hi = HB;
  float baseS = 0.f;
  for (int it = 0; it < 14; ++it) {
    int mid = (lo + hi) >> 1;
    float p = 0.f;
    if (tid < 256) p = qs[tid] * (float)cdfT[(size_t)mid * 256 + tid];
    float r = p;
    #pragma unroll
    for (int off = 32; off; off >>= 1) r += __shfl_xor(r, off);
    if (lane == 0) red[wv] = r;
    __syncthreads();
    if (tid == 0) {
      float s = 0.f;
      for (int w = 0; w < 8; ++w) s += red[w];
      bc[1] = s;
    }
    __syncthreads();
    float S = bc[1];
    if (S < R) { lo = mid; baseS = S; } else { hi = mid; }
  }
  const int B = lo;  // crossing bucket; baseS = weighted count below it

  // ---- gather bucket B members into 4096-bin weighted histogram of lo16>>4 ----
  {
    const int n = tid >> 1;
    const float q = qs[n];
    const unsigned short* cn = cdf + (size_t)n * CDF_STRIDE;
    const unsigned short* gn = grouped + (size_t)n * NPIX;
    unsigned e0 = cn[B + 1];
    for (unsigned j = (unsigned)cn[B] + (tid & 1); j < e0; j += 2)
      atomicAdd(&bins[gn[j] >> 4], q);
  }
  __syncthreads();

  // ---- wave 0: scan 4096 bins, find crossing bin ----
  if (wv == 0) {
    float s = 0.f;
    for (int j = 0; j < 64; ++j) s += bins[lane * 64 + j];
    float inc = s;
    #pragma unroll
    for (int off = 1; off < 64; off <<= 1) {
      float u = __shfl_up(inc, off);
      if (lane >= off) inc += u;
    }
    float pre = inc - s;
    bool hit = (baseS + pre < R) && (baseS + inc >= R);
    unsigned long long m = __ballot(hit);
    int ow = m ? (__ffsll((unsigned long long)m) - 1) : -1;
    if (lane == ow) {
      float run = baseS + pre;
      unsigned bin = (unsigned)lane * 64 + 63;
      for (int j = 0; j < 64; ++j) {
        float bv = bins[lane * 64 + j];
        if (run + bv >= R) { bin = (unsigned)lane * 64 + j; break; }
        run += bv;
      }
      sBin = bin;
    }
    if (m == 0 && lane == 0) sBin = 4095u;  // f32-rounding fallback (unreachable in practice)
  }
  __syncthreads();
  if (tid == 0) {
    unsigned tb = ((unsigned)B << 16) | (sBin << 4);
    lam[b] = 1.0f - __uint_as_float(tb | 0x8u);     // mid-bin representative
    thr[b] = __uint_as_float((tb | 0xFu) + 1u);     // strictly above bin top: pred = res > u*
  }
}

// ---- final partials + output: grid (32 samples, 8 segments) ----
// Absorbs k_out: the 8th-arriving segment block per sample reads the device-scope
// accumulated counts and writes out[] directly (saves a launch).
__global__ __launch_bounds__(256) void k_finalp(const float* __restrict__ tres,
                                                const int* __restrict__ tgt,
                                                const float* __restrict__ thr,
                                                const float* __restrict__ lam,
                                                int* __restrict__ facc,
                                                float* __restrict__ out) {
  __shared__ int red[12];
  const int b = blockIdx.x, seg = blockIdx.y, tid = threadIdx.x;
  const int lane = tid & 63, wv = tid >> 6;
  const float th = thr[b];
  const float4* rb4 = (const float4*)(tres + (size_t)b * NPIX + seg * 8192);
  const int4* gb4 = (const int4*)(tgt + (size_t)b * NPIX + seg * 8192);
  int sz = 0, tp = 0, tpos = 0;
  #pragma unroll
  for (int i = 0; i < 8; ++i) {
    float4 r4 = rb4[i * 256 + tid];
    int4 g4 = gb4[i * 256 + tid];
    int p0 = (r4.x >= th), t0 = (g4.x > 0);
    int p1 = (r4.y >= th), t1 = (g4.y > 0);
    int p2 = (r4.z >= th), t2 = (g4.z > 0);
    int p3 = (r4.w >= th), t3 = (g4.w > 0);
    sz += p0 + p1 + p2 + p3;
    tp += (p0 & t0) + (p1 & t1) + (p2 & t2) + (p3 & t3);
    tpos += t0 + t1 + t2 + t3;
  }
  #pragma unroll
  for (int off = 32; off; off >>= 1) {
    sz += __shfl_xor(sz, off);
    tp += __shfl_xor(tp, off);
    tpos += __shfl_xor(tpos, off);
  }
  if (lane == 0) { red[wv] = sz; red[4 + wv] = tp; red[8 + wv] = tpos; }
  __syncthreads();
  if (tid == 0) {
    int s0 = red[0] + red[1] + red[2] + red[3];
    int s1 = red[4] + red[5] + red[6] + red[7];
    int s2 = red[8] + red[9] + red[10] + red[11];
    atomicAdd(&facc[b * 4 + 0], s0);
    atomicAdd(&facc[b * 4 + 1], s1);
    atomicAdd(&facc[b * 4 + 2], s2);
    __threadfence();  // publish before arrival
    int done = atomicAdd(&facc[b * 4 + 3], 1);
    if (done == 7) {  // last of 8 segment blocks: all adds are visible via atomics
      int f0 = atomicAdd(&facc[b * 4 + 0], 0);
      int f1 = atomicAdd(&facc[b * 4 + 1], 0);
      int f2 = atomicAdd(&facc[b * 4 + 2], 0);
      float tposf = (float)(f2 > 0 ? f2 : 1);
      out[b] = 1.f - (float)f1 / tposf;   // fnr_test
      out[32 + b] = lam[b];               // lambda
      out[64 + b] = (float)f0;            // size
    }
  }
}

extern "C" void kernel_launch(void* const* d_in, const int* in_sizes, int n_in,
                              void* d_out, int out_size, void* d_ws, size_t ws_size,
                              hipStream_t stream) {
  const float* cal_feat = (const float*)d_in[0];
  const float* test_feat = (const float*)d_in[1];
  const int* cal_gt = (const int*)d_in[2];
  const int* test_gt = (const int*)d_in[3];
  float* out = (float*)d_out;
  char* ws = (char*)d_ws;

  float* test_res = (float*)(ws + OFF_TESTRES);
  unsigned short* cal_bf = (unsigned short*)(ws + OFF_CALBF);
  unsigned short* test_bf = (unsigned short*)(ws + OFF_TESTBF);
  unsigned short* grouped = (unsigned short*)(ws + OFF_GROUPED);
  unsigned short* cdf = (unsigned short*)(ws + OFF_CDF);
  unsigned short* cdfT = (unsigned short*)(ws + OFF_CDFT);
  float* gpart = (float*)(ws + OFF_GPART);
  float* cc = (float*)(ws + OFF_CC);
  float* thr = (float*)(ws + OFF_THR);
  float* lam = (float*)(ws + OFF_LAM);
  int* facc = (int*)(ws + OFF_FACC);

  k_calt<<<dim3(256), dim3(1024), 0, stream>>>(cal_feat, cal_gt, cal_bf, cdf, grouped, cc,
                                               test_feat, test_res, test_bf);
  k_gemmtr<<<dim3(8, 65), dim3(256), 0, stream>>>(test_bf, cal_bf, gpart, cdf, cdfT);
  k_quantw<<<dim3(32), dim3(512), 0, stream>>>(gpart, cc, test_bf, cdf, cdfT, grouped,
                                               lam, thr, facc);
  k_finalp<<<dim3(32, 8), dim3(256), 0, stream>>>(test_res, test_gt, thr, lam, facc, out);
}

// Round 9
// 227.072 us; speedup vs baseline: 1.2032x; 1.2032x over previous
//
#include <hip/hip_runtime.h>

// RandomlyLocalizedConformalRiskControl on MI355X.
// ws layout (bytes), total ~98.4 MB:
//   test_res f32 [32][65536]             @ 0          (8 MB)    f32 scores for final scan
//   cal_bf   u16 [256][65536]            @ 8388608    (32 MB)   bf16 cal scores (MFMA A/B)
//   test_bf  u16 [32][65536]             @ 41943040   (4 MB)    bf16 test scores
//   grouped  u16 [256][65536]            @ 46137344   (32 MB)   low-16 bits of f32 score, grouped by hi-16 bucket
//   cdf      u16 [256][CDF_STRIDE]       @ 79691776   (8.3 MB)  exclusive CDF, row-major (gather/pos)
//   gpart    f32 [64][8][1024]           @ 88023040   (2 MB)    split-K MFMA partials (deterministic)
//   cc f32[256], thr f32[32], lam f32[32], facc i32[32][4]
//   cdfT     u16 [16256][256]            @ 90122240   (8.3 MB)  TRANSPOSED cdf: coalesced binary search
// Pipeline (4 launches): k_calt -> k_gemmtr (GEMM y<64 + 128-block transpose y>=64)
// -> k_quantw -> k_finalp (absorbs k_out).

#define NPIX 65536
#define HB 16256            // buckets = float_bits >> 16 for scores in (0, 1.0]
#define CDF_STRIDE 16272
#define ALPHA 0.1f
#define STAGE_CAP 35840     // u16 staging entries; pos ~ Bin(65536,1/2) max ~33.4K (+24 sigma)

#define OFF_TESTRES  0
#define OFF_CALBF    8388608u
#define OFF_TESTBF   41943040u
#define OFF_GROUPED  46137344u
#define OFF_CDF      79691776u
#define OFF_GPART    88023040u
#define OFF_CC       90120192u
#define OFF_THR      90121216u
#define OFF_LAM      90121344u
#define OFF_FACC     90121472u
#define OFF_CDFT     90122240u

typedef __attribute__((ext_vector_type(8))) short bf16x8;
typedef __attribute__((ext_vector_type(16))) float f32x16;

__device__ __forceinline__ unsigned f2bf_rne(float f) {
  unsigned u = __float_as_uint(f);
  return (u + 0x7FFFu + ((u >> 16) & 1u)) >> 16;
}

// XOR swizzle on bucket index: involution, closed within each 32-word block.
__device__ __forceinline__ int SW(int w) { return w ^ ((w >> 5) & 31); }

// The sigmoid tail shared by ALL score evaluation sites: identical inlined expression
// tree -> identical FMA contraction -> bit-identical f32 on every recompute/reuse.
__device__ __forceinline__ float sig_v(float a, float b, float wy) {
  float v = a * (1.f - wy) + b * wy;
  return 1.f / (1.f + __expf(-v));
}

// Row x-interp for the 4 pixels of a thread's patch: SAME source expression shape as
// the original score_at row interp (f[x0]*(1-wx) + f[x1]*wx with runtime wx), operands
// pre-selected per-k (cL/cM/cR reproduce the clamped x0/x1 pairs exactly, including
// the x=0 / x=255 both-operands-equal corner cases).
#define ROWH(F, r, h0, h1, h2, h3)                                        \
  {                                                                       \
    float fL_ = (F)[(r) * 64 + cL];                                       \
    float fM_ = (F)[(r) * 64 + cM];                                       \
    float fR_ = (F)[(r) * 64 + cR];                                       \
    h0 = fL_ * (1.f - wx0) + fM_ * wx0;                                   \
    h1 = fL_ * (1.f - wx1) + fM_ * wx1;                                   \
    h2 = fM_ * (1.f - wx2) + fR_ * wx2;                                   \
    h3 = fM_ * (1.f - wx3) + fR_ * wx3;                                   \
  }

// ---- fused cal+test features, 256 blocks (one per cal sample) ----
// 4-pixel-wide patches (R8): thread (xg, band) owns x=4xg..4xg+3, rows [16*band,+16).
// __launch_bounds__(1024, 1): LDS (157.7 KB) limits to 1 block/CU anyway; the old
// (1024,2) capped VGPR at 64 and the patch registers spilled to scratch (R8: FETCH
// +11 MB, WRITE +24 MB). 1 wave/EU floor frees the allocator (cap 512) -> no spill.
// smem map (u32): [0,16256) hist -> CDF -> scatter counters (swizzled); [16256,16272)
// scan wave totals; [16272,16288) cc partials; [16288,17312) thread prefixes; [17312] pos.
__global__ __launch_bounds__(1024, 1) void k_calt(const float* __restrict__ featc,
                                                  const int* __restrict__ gt,
                                                  unsigned short* __restrict__ calbf,
                                                  unsigned short* __restrict__ cdf,
                                                  unsigned short* __restrict__ grouped,
                                                  float* __restrict__ cc,
                                                  const float* __restrict__ featt,
                                                  float* __restrict__ tres,
                                                  unsigned short* __restrict__ tbf) {
  __shared__ unsigned smem[17313];
  __shared__ float sfeat[4096];
  __shared__ __align__(16) unsigned short sstage[STAGE_CAP];
  float* tfeat = (float*)sstage;                    // sstage[0..8191]: dead before phase B
  unsigned* gmask = (unsigned*)(sstage + 8192);     // sstage[8192..12287]: dead before phase B
  const int tid = threadIdx.x;
  const int lane = tid & 63, wv = tid >> 6;
  const int xg = tid & 63, band = tid >> 6;  // patch col group / 16-row band
  // per-k x-interp params: identical per-pixel computation as before (x = 4*xg + k)
  float wx0, wx1, wx2, wx3;
  {
    float sx0 = 0.25f * (float)(4 * xg + 0) - 0.375f;
    float sx1 = 0.25f * (float)(4 * xg + 1) - 0.375f;
    float sx2 = 0.25f * (float)(4 * xg + 2) - 0.375f;
    float sx3 = 0.25f * (float)(4 * xg + 3) - 0.375f;
    wx0 = sx0 - (float)((int)floorf(sx0));
    wx1 = sx1 - (float)((int)floorf(sx1));
    wx2 = sx2 - (float)((int)floorf(sx2));
    wx3 = sx3 - (float)((int)floorf(sx3));
  }
  const int cL = (xg == 0) ? 0 : xg - 1;
  const int cM = xg;
  const int cR = (xg == 63) ? 63 : xg + 1;

  const int n = blockIdx.x;
  const int b = n >> 3, sl = n & 7;  // test sample + slice handled by this block
  for (int i = tid; i < HB; i += 1024) smem[i] = 0;
  for (int i = tid; i < 4096; i += 1024) {
    sfeat[i] = featc[n * 4096 + i];
    tfeat[i] = featt[b * 4096 + i];
  }
  // gt bitmask pre-pass: coalesced int4 loads -> 8 KB LDS bitmask
  {
    const int4* gt4 = (const int4*)(gt + (size_t)n * NPIX);
    for (int w = tid; w < 2048; w += 1024) {
      unsigned m = 0;
      #pragma unroll
      for (int j = 0; j < 8; ++j) {
        int4 g = gt4[w * 8 + j];
        m |= (g.x > 0 ? 1u : 0u) << (j * 4);
        m |= (g.y > 0 ? 2u : 0u) << (j * 4);
        m |= (g.z > 0 ? 4u : 0u) << (j * 4);
        m |= (g.w > 0 ? 8u : 0u) << (j * 4);
      }
      gmask[w] = m;
    }
  }
  unsigned short* cbn = calbf + (size_t)n * NPIX;
  __syncthreads();  // S0: feats + hist + gmask ready

  // ---- test slice: rows {sl*32+2*band, +1} x cols 4xg..4xg+3 (one quad window) ----
  {
    const int tr0 = sl * 32 + 2 * band;
    const int mt = tr0 >> 2, j0 = tr0 & 3;  // quad, first row-in-quad (0 or 2)
    float tp0, tp1, tp2, tp3, tc0, tc1, tc2, tc3, tn0, tn1, tn2, tn3;
    int rp = (mt == 0) ? 0 : mt - 1;
    int rn = (mt == 63) ? 63 : mt + 1;
    ROWH(tfeat, rp, tp0, tp1, tp2, tp3);
    ROWH(tfeat, mt, tc0, tc1, tc2, tc3);
    ROWH(tfeat, rn, tn0, tn1, tn2, tn3);
    float* resb = tres + (size_t)b * NPIX;
    unsigned short* tbn = tbf + (size_t)b * NPIX;
    #pragma unroll
    for (int jj = 0; jj < 2; ++jj) {
      int j = j0 + jj;
      int y = 4 * mt + j;
      float sy = 0.25f * (float)y - 0.375f;
      int y0i = (int)floorf(sy);
      float wy = sy - (float)y0i;
      float a0 = j < 2 ? tp0 : tc0, b0 = j < 2 ? tc0 : tn0;
      float a1 = j < 2 ? tp1 : tc1, b1 = j < 2 ? tc1 : tn1;
      float a2 = j < 2 ? tp2 : tc2, b2 = j < 2 ? tc2 : tn2;
      float a3 = j < 2 ? tp3 : tc3, b3 = j < 2 ? tc3 : tn3;
      float s0 = sig_v(a0, b0, wy), s1 = sig_v(a1, b1, wy);
      float s2 = sig_v(a2, b2, wy), s3 = sig_v(a3, b3, wy);
      float4 rv = {s0, s1, s2, s3};
      *(float4*)(resb + (y << 8) + 4 * xg) = rv;
      uint2 pk;
      pk.x = f2bf_rne(s0) | (f2bf_rne(s1) << 16);
      pk.y = f2bf_rne(s2) | (f2bf_rne(s3) << 16);
      *(uint2*)(tbn + (y << 8) + 4 * xg) = pk;
    }
  }

  // ---- cal phase A: 4-wide patch scores, packed stores, bitmask, hist, cc ----
  const int mq0 = band * 4;  // quads mq0..mq0+3 (rows 16*band..+15)
  unsigned long long pm = 0ull;
  float sumsq = 0.f;
  {
    float hp0, hp1, hp2, hp3, hc0, hc1, hc2, hc3, hn0, hn1, hn2, hn3;
    int rp = (mq0 == 0) ? 0 : mq0 - 1;
    ROWH(sfeat, rp, hp0, hp1, hp2, hp3);
    ROWH(sfeat, mq0, hc0, hc1, hc2, hc3);
    for (int qq = 0; qq < 4; ++qq) {
      int m = mq0 + qq;
      int rn = (m == 63) ? 63 : m + 1;
      ROWH(sfeat, rn, hn0, hn1, hn2, hn3);
      #pragma unroll
      for (int j = 0; j < 4; ++j) {
        int y = 4 * m + j;
        float sy = 0.25f * (float)y - 0.375f;
        int y0i = (int)floorf(sy);
        float wy = sy - (float)y0i;
        float a0 = j < 2 ? hp0 : hc0, b0 = j < 2 ? hc0 : hn0;
        float a1 = j < 2 ? hp1 : hc1, b1 = j < 2 ? hc1 : hn1;
        float a2 = j < 2 ? hp2 : hc2, b2 = j < 2 ? hc2 : hn2;
        float a3 = j < 2 ? hp3 : hc3, b3 = j < 2 ? hc3 : hn3;
        float s0 = sig_v(a0, b0, wy), s1 = sig_v(a1, b1, wy);
        float s2 = sig_v(a2, b2, wy), s3 = sig_v(a3, b3, wy);
        unsigned u0 = f2bf_rne(s0), u1 = f2bf_rne(s1);
        unsigned u2 = f2bf_rne(s2), u3 = f2bf_rne(s3);
        uint2 pk;
        pk.x = u0 | (u1 << 16);
        pk.y = u2 | (u3 << 16);
        *(uint2*)(cbn + (y << 8) + 4 * xg) = pk;
        float r0 = __uint_as_float(u0 << 16), r1 = __uint_as_float(u1 << 16);
        float r2 = __uint_as_float(u2 << 16), r3 = __uint_as_float(u3 << 16);
        sumsq += r0 * r0;
        sumsq += r1 * r1;
        sumsq += r2 * r2;
        sumsq += r3 * r3;
        unsigned nib = (gmask[(y << 3) + (xg >> 3)] >> (4 * (xg & 7))) & 0xFu;
        if (nib & 1u) {
          pm |= 1ull << (qq * 16 + j * 4 + 0);
          atomicAdd(&smem[SW((int)(__float_as_uint(s0) >> 16))], 1u);
        }
        if (nib & 2u) {
          pm |= 1ull << (qq * 16 + j * 4 + 1);
          atomicAdd(&smem[SW((int)(__float_as_uint(s1) >> 16))], 1u);
        }
        if (nib & 4u) {
          pm |= 1ull << (qq * 16 + j * 4 + 2);
          atomicAdd(&smem[SW((int)(__float_as_uint(s2) >> 16))], 1u);
        }
        if (nib & 8u) {
          pm |= 1ull << (qq * 16 + j * 4 + 3);
          atomicAdd(&smem[SW((int)(__float_as_uint(s3) >> 16))], 1u);
        }
      }
      hp0 = hc0; hp1 = hc1; hp2 = hc2; hp3 = hc3;
      hc0 = hn0; hc1 = hn1; hc2 = hn2; hc3 = hn3;
    }
  }
  // cc partials (16 waves); band-patch accumulation order (reassociation accepted)
  #pragma unroll
  for (int off = 32; off; off >>= 1) sumsq += __shfl_xor(sumsq, off);
  if (lane == 0) smem[16272 + wv] = __float_as_uint(sumsq);
  __syncthreads();  // S1: hist + cc partials final
  if (tid == 0) {
    float c = 0.f;
    for (int w = 0; w < 16; ++w) c += __uint_as_float(smem[16272 + w]);
    cc[n] = c;
  }
  // ---- exclusive scan: threads 0..1015, 16 buckets each ----
  const int base = tid * 16;
  unsigned psum = 0;
  if (tid < 1016) {
    #pragma unroll
    for (int j = 0; j < 16; ++j) psum += smem[SW(base + j)];
  }
  unsigned inc = psum;
  #pragma unroll
  for (int off = 1; off < 64; off <<= 1) {
    unsigned v = __shfl_up(inc, off);
    if (lane >= off) inc += v;
  }
  if (lane == 63) smem[16256 + wv] = inc;  // wave totals
  smem[16288 + tid] = inc - psum;          // thread-exclusive prefix within wave
  __syncthreads();  // S2: totals + prefixes ready
  {
    unsigned woff = 0;
    for (int w = 0; w < wv; ++w) woff += smem[16256 + w];  // broadcast reads
    unsigned run = woff + smem[16288 + tid];
    if (tid < 1016) {
      #pragma unroll
      for (int j = 0; j < 16; ++j) {
        int si = SW(base + j);
        unsigned h = smem[si];
        smem[si] = run;  // exclusive CDF -> scatter counters
        run += h;
      }
    }
    if (tid == 1015) smem[17312] = run;  // total positives (lanes above 1015 hold 0)
  }
  __syncthreads();  // S2b: counters final
  // ---- COALESCED u16 cdf copyout ----
  unsigned short* cdfn = cdf + (size_t)n * CDF_STRIDE;
  for (int i = tid; i < HB; i += 1024) cdfn[i] = (unsigned short)smem[SW(i)];
  const unsigned pos = smem[17312];
  if (tid == 0) cdfn[HB] = (unsigned short)pos;  // pos < 2^16 for Bin(65536,1/2) data
  __syncthreads();  // S3: cdf written before counters mutate
  // ---- phase B: patch recompute (bit-exact expression reuse), LDS staging ----
  unsigned short* gn = grouped + (size_t)n * NPIX;
  {
    float hp0, hp1, hp2, hp3, hc0, hc1, hc2, hc3, hn0, hn1, hn2, hn3;
    int rp = (mq0 == 0) ? 0 : mq0 - 1;
    ROWH(sfeat, rp, hp0, hp1, hp2, hp3);
    ROWH(sfeat, mq0, hc0, hc1, hc2, hc3);
    for (int qq = 0; qq < 4; ++qq) {
      int m = mq0 + qq;
      int rn = (m == 63) ? 63 : m + 1;
      ROWH(sfeat, rn, hn0, hn1, hn2, hn3);
      unsigned qb = (unsigned)(pm >> (qq * 16)) & 0xFFFFu;
      if (qb) {
        #pragma unroll
        for (int j = 0; j < 4; ++j) {
          unsigned nib = (qb >> (j * 4)) & 0xFu;
          if (nib) {
            int y = 4 * m + j;
            float sy = 0.25f * (float)y - 0.375f;
            int y0i = (int)floorf(sy);
            float wy = sy - (float)y0i;
            float a0 = j < 2 ? hp0 : hc0, b0 = j < 2 ? hc0 : hn0;
            float a1 = j < 2 ? hp1 : hc1, b1 = j < 2 ? hc1 : hn1;
            float a2 = j < 2 ? hp2 : hc2, b2 = j < 2 ? hc2 : hn2;
            float a3 = j < 2 ? hp3 : hc3, b3 = j < 2 ? hc3 : hn3;
            #pragma unroll
            for (int k = 0; k < 4; ++k) {
              if (nib & (1u << k)) {
                float s = k == 0 ? sig_v(a0, b0, wy)
                        : k == 1 ? sig_v(a1, b1, wy)
                        : k == 2 ? sig_v(a2, b2, wy)
                                 : sig_v(a3, b3, wy);
                unsigned bits = __float_as_uint(s);
                unsigned idx = atomicAdd(&smem[SW((int)(bits >> 16))], 1u);
                unsigned short lo = (unsigned short)(bits & 0xFFFFu);
                if (idx < STAGE_CAP) sstage[idx] = lo;
                else gn[idx] = lo;  // overflow fallback: same final location
              }
            }
          }
        }
      }
      hp0 = hc0; hp1 = hc1; hp2 = hc2; hp3 = hc3;
      hc0 = hn0; hc1 = hn1; hc2 = hn2; hc3 = hn3;
    }
  }
  __syncthreads();  // S4: staging complete
  // ---- COALESCED grouped copyout ----
  unsigned lim = pos < STAGE_CAP ? pos : STAGE_CAP;
  for (unsigned i = tid; i < lim; i += 1024) gn[i] = sstage[i];
}

// ---- merged GEMM + cdf transpose; grid (8, 80): y<64 GEMM, y>=64 transpose ----
// GEMM: gpart[ks][nt][m*32+nl] = <test_m, cal_(nt*32+nl)>, LDS-staged, XOR-swizzled,
// 32x32x16 bf16 MFMA, wave = K-quarter split, cross-wave reduce in lred.
// Transpose: 128 blocks, ONE 128-bucket tile each (R8's 8-block version serialized the
// latency-bound uncoalesced read side 16x -> +65 us; full block parallelism restored).
// cdfT[bucket][n] = cdf[n][bucket] — faithful copy, bit-exact search input.
__global__ __launch_bounds__(256) void k_gemmtr(const unsigned short* __restrict__ tbf,
                                                const unsigned short* __restrict__ cbf,
                                                float* __restrict__ gpart,
                                                const unsigned short* __restrict__ cdf,
                                                unsigned short* __restrict__ cdfT) {
  __shared__ __align__(16) char lds[81920];
  const int tid = threadIdx.x;
  if (blockIdx.y >= 64) {
    // ---- transpose role: tile t = (y-64)*8 + x in [0,127) ----
    const int t = (blockIdx.y - 64) * 8 + blockIdx.x;
    if (t >= 127) return;
    unsigned short (*tile)[136] = (unsigned short (*)[136])lds;  // 16B-aligned rows
    const int b0 = t * 128;
    const unsigned short* src = cdf + (size_t)tid * CDF_STRIDE + b0;
    #pragma unroll
    for (int j = 0; j < 128; j += 8)
      *(int4*)&tile[tid][j] = *(const int4*)(src + j);
    __syncthreads();
    for (int j = 0; j < 128; ++j)
      cdfT[(size_t)(b0 + j) * 256 + tid] = tile[tid][j];
    return;
  }
  // ---- GEMM role ----
  unsigned short* As = (unsigned short*)lds;            // 32 KB
  unsigned short* Bs = (unsigned short*)(lds + 32768);  // 32 KB
  float (*lred)[1024] = (float (*)[1024])(lds + 65536); // 16 KB
  const int lane = tid & 63, wv = tid >> 6;
  const int r = lane & 31, half = lane >> 5;
  const int nt = blockIdx.x;              // 0..7: cal column tile
  f32x16 acc;
  #pragma unroll
  for (int i = 0; i < 16; ++i) acc[i] = 0.f;
  for (int ch = 0; ch < 2; ++ch) {        // two 512-K chunks of this block's 1024-K slice
    const size_t kbase = (size_t)blockIdx.y * 1024 + ch * 512;
    __syncthreads();
    #pragma unroll
    for (int s = 0; s < 16; ++s) {
      int flat = s * 256 + tid;           // 0..4095; <2048 = A, else B (wave-uniform per s)
      int rem = flat & 2047;
      int row = rem >> 6, kb = rem & 63;
      const unsigned short* src = (flat >= 2048)
          ? cbf + (size_t)(nt * 32 + row) * NPIX + kbase + kb * 8
          : tbf + (size_t)row * NPIX + kbase + kb * 8;
      int slot = ((kb << 5) + row) ^ (kb & 31);   // XOR swizzle breaks write-bank collisions
      int4 v = *(const int4*)src;
      *(int4*)((flat >= 2048 ? Bs : As) + slot * 8) = v;
    }
    __syncthreads();
    #pragma unroll
    for (int i = 0; i < 8; ++i) {         // wave's K-quarter: kblk in [wv*16, wv*16+16)
      int k8 = (wv << 4) + i * 2 + half;
      int slot = ((k8 << 5) + r) ^ (k8 & 31);
      bf16x8 a = *(const bf16x8*)(As + slot * 8);
      bf16x8 b = *(const bf16x8*)(Bs + slot * 8);
      acc = __builtin_amdgcn_mfma_f32_32x32x16_bf16(a, b, acc, 0, 0, 0);
    }
  }
  // C/D layout (HW-verified): col = lane&31, row = (reg&3) + 8*(reg>>2) + 4*(lane>>5)
  #pragma unroll
  for (int rg = 0; rg < 16; ++rg) {
    int m = (rg & 3) + 8 * (rg >> 2) + 4 * half;
    lred[wv][m * 32 + r] = acc[rg];
  }
  __syncthreads();
  float* gp = gpart + (size_t)(blockIdx.y * 8 + nt) * 1024;
  for (int e = tid; e < 1024; e += 256)
    gp[e] = lred[0][e] + lred[1][e] + lred[2][e] + lred[3][e];
}

// ---- tt + weights + weighted-quantile; zero-inits facc; writes thr/lam ----
__global__ __launch_bounds__(512) void k_quantw(const float* __restrict__ gpart,
                                                const float* __restrict__ cc,
                                                const unsigned short* __restrict__ tbf,
                                                const unsigned short* __restrict__ cdf,
                                                const unsigned short* __restrict__ cdfT,
                                                const unsigned short* __restrict__ grouped,
                                                float* __restrict__ lam,
                                                float* __restrict__ thr,
                                                int* __restrict__ facc) {
  __shared__ float qs[256];
  __shared__ float bins[4096];
  __shared__ float red[8];
  __shared__ float tpart[16];
  __shared__ float bc[3];      // [0]=wsum [1]=S(mid) [2]=tt
  __shared__ unsigned sBin;
  const int b = blockIdx.x, tid = threadIdx.x;
  const int lane = tid & 63, wv = tid >> 6;

  if (tid < 4) facc[b * 4 + tid] = 0;
  for (int i = tid; i < 4096; i += 512) bins[i] = 0.f;
  if (tid == 0) sBin = 0xFFFFFFFFu;

  // ---- tt[b]: bit-exact virtual-thread replica of the original 1024-thread reduction ----
  {
    const unsigned short* tbn = tbf + (size_t)b * NPIX;
    const int xa = tid & 255, ya = tid >> 8;        // virtual thread vt = tid
    const int yb = ya + 2;                          // virtual thread vt = tid + 512
    float sa = 0.f, sb = 0.f;
    #pragma unroll 4
    for (int it = 0; it < 64; ++it) {
      float ra = __uint_as_float((unsigned)tbn[((it * 4 + ya) << 8) + xa] << 16);
      float rb = __uint_as_float((unsigned)tbn[((it * 4 + yb) << 8) + xa] << 16);
      sa += ra * ra;
      sb += rb * rb;
    }
    #pragma unroll
    for (int off = 32; off; off >>= 1) {
      sa += __shfl_xor(sa, off);
      sb += __shfl_xor(sb, off);
    }
    if (lane == 0) { tpart[wv] = sa; tpart[8 + wv] = sb; }
  }
  __syncthreads();
  if (tid == 0) {
    float t = 0.f;
    for (int w = 0; w < 16; ++w) t += tpart[w];
    bc[2] = t;
  }
  // ---- weights g-sum (independent of tt) ----
  float g = 0.f;
  if (tid < 256) {
    const float* gp = gpart + ((tid >> 5) * 1024) + (b * 32) + (tid & 31);
    #pragma unroll 8
    for (int ks = 0; ks < 64; ++ks) g += gp[(size_t)ks * 8192];
  }
  __syncthreads();  // bc[2] visible
  float k = 0.f;
  if (tid < 256) {
    float d2 = bc[2] + cc[tid] - 2.f * g;
    k = expf(-d2 * (1.f / 8192.f));
  }
  float v = k;
  #pragma unroll
  for (int off = 32; off; off >>= 1) v += __shfl_xor(v, off);
  if (lane == 0) red[wv] = v;
  __syncthreads();
  if (tid == 0) {
    float ws = 1.f;
    for (int w = 0; w < 8; ++w) ws += red[w];
    bc[0] = ws;
  }
  __syncthreads();
  const float wsum = bc[0];
  const float wlast = 1.f / wsum;
  const float R = ALPHA - wlast;
  if (R <= 0.f) {  // risk >= alpha for every lam -> low -> 1.0f, thr 0 (predict all)
    if (tid == 0) { lam[b] = 1.0f; thr[b] = 0.0f; }
    return;
  }
  if (tid < 256) {
    unsigned pos = cdf[(size_t)tid * CDF_STRIDE + HB];
    qs[tid] = k / (wsum * (float)(pos ? pos : 1u));
  }
  __syncthreads();

  // ---- 14-step binary search over hi-16 buckets (coalesced via cdfT) ----
  int lo = 0, hi = HB;
  float baseS = 0.f;
  for (int it = 0; it < 14; ++it) {
    int mid = (lo + hi) >> 1;
    float p = 0.f;
    if (tid < 256) p = qs[tid] * (float)cdfT[(size_t)mid * 256 + tid];
    float r = p;
    #pragma unroll
    for (int off = 32; off; off >>= 1) r += __shfl_xor(r, off);
    if (lane == 0) red[wv] = r;
    __syncthreads();
    if (tid == 0) {
      float s = 0.f;
      for (int w = 0; w < 8; ++w) s += red[w];
      bc[1] = s;
    }
    __syncthreads();
    float S = bc[1];
    if (S < R) { lo = mid; baseS = S; } else { hi = mid; }
  }
  const int B = lo;  // crossing bucket; baseS = weighted count below it

  // ---- gather bucket B members into 4096-bin weighted histogram of lo16>>4 ----
  {
    const int n = tid >> 1;
    const float q = qs[n];
    const unsigned short* cn = cdf + (size_t)n * CDF_STRIDE;
    const unsigned short* gn = grouped + (size_t)n * NPIX;
    unsigned e0 = cn[B + 1];
    for (unsigned j = (unsigned)cn[B] + (tid & 1); j < e0; j += 2)
      atomicAdd(&bins[gn[j] >> 4], q);
  }
  __syncthreads();

  // ---- wave 0: scan 4096 bins, find crossing bin ----
  if (wv == 0) {
    float s = 0.f;
    for (int j = 0; j < 64; ++j) s += bins[lane * 64 + j];
    float inc = s;
    #pragma unroll
    for (int off = 1; off < 64; off <<= 1) {
      float u = __shfl_up(inc, off);
      if (lane >= off) inc += u;
    }
    float pre = inc - s;
    bool hit = (baseS + pre < R) && (baseS + inc >= R);
    unsigned long long m = __ballot(hit);
    int ow = m ? (__ffsll((unsigned long long)m) - 1) : -1;
    if (lane == ow) {
      float run = baseS + pre;
      unsigned bin = (unsigned)lane * 64 + 63;
      for (int j = 0; j < 64; ++j) {
        float bv = bins[lane * 64 + j];
        if (run + bv >= R) { bin = (unsigned)lane * 64 + j; break; }
        run += bv;
      }
      sBin = bin;
    }
    if (m == 0 && lane == 0) sBin = 4095u;  // f32-rounding fallback (unreachable in practice)
  }
  __syncthreads();
  if (tid == 0) {
    unsigned tb = ((unsigned)B << 16) | (sBin << 4);
    lam[b] = 1.0f - __uint_as_float(tb | 0x8u);     // mid-bin representative
    thr[b] = __uint_as_float((tb | 0xFu) + 1u);     // strictly above bin top: pred = res > u*
  }
}

// ---- final partials + output: grid (32 samples, 8 segments) ----
// Absorbs k_out: the 8th-arriving segment block per sample reads the device-scope
// accumulated counts and writes out[] directly (saves a launch).
__global__ __launch_bounds__(256) void k_finalp(const float* __restrict__ tres,
                                                const int* __restrict__ tgt,
                                                const float* __restrict__ thr,
                                                const float* __restrict__ lam,
                                                int* __restrict__ facc,
                                                float* __restrict__ out) {
  __shared__ int red[12];
  const int b = blockIdx.x, seg = blockIdx.y, tid = threadIdx.x;
  const int lane = tid & 63, wv = tid >> 6;
  const float th = thr[b];
  const float4* rb4 = (const float4*)(tres + (size_t)b * NPIX + seg * 8192);
  const int4* gb4 = (const int4*)(tgt + (size_t)b * NPIX + seg * 8192);
  int sz = 0, tp = 0, tpos = 0;
  #pragma unroll
  for (int i = 0; i < 8; ++i) {
    float4 r4 = rb4[i * 256 + tid];
    int4 g4 = gb4[i * 256 + tid];
    int p0 = (r4.x >= th), t0 = (g4.x > 0);
    int p1 = (r4.y >= th), t1 = (g4.y > 0);
    int p2 = (r4.z >= th), t2 = (g4.z > 0);
    int p3 = (r4.w >= th), t3 = (g4.w > 0);
    sz += p0 + p1 + p2 + p3;
    tp += (p0 & t0) + (p1 & t1) + (p2 & t2) + (p3 & t3);
    tpos += t0 + t1 + t2 + t3;
  }
  #pragma unroll
  for (int off = 32; off; off >>= 1) {
    sz += __shfl_xor(sz, off);
    tp += __shfl_xor(tp, off);
    tpos += __shfl_xor(tpos, off);
  }
  if (lane == 0) { red[wv] = sz; red[4 + wv] = tp; red[8 + wv] = tpos; }
  __syncthreads();
  if (tid == 0) {
    int s0 = red[0] + red[1] + red[2] + red[3];
    int s1 = red[4] + red[5] + red[6] + red[7];
    int s2 = red[8] + red[9] + red[10] + red[11];
    atomicAdd(&facc[b * 4 + 0], s0);
    atomicAdd(&facc[b * 4 + 1], s1);
    atomicAdd(&facc[b * 4 + 2], s2);
    __threadfence();  // publish before arrival
    int done = atomicAdd(&facc[b * 4 + 3], 1);
    if (done == 7) {  // last of 8 segment blocks: all adds are visible via atomics
      int f0 = atomicAdd(&facc[b * 4 + 0], 0);
      int f1 = atomicAdd(&facc[b * 4 + 1], 0);
      int f2 = atomicAdd(&facc[b * 4 + 2], 0);
      float tposf = (float)(f2 > 0 ? f2 : 1);
      out[b] = 1.f - (float)f1 / tposf;   // fnr_test
      out[32 + b] = lam[b];               // lambda
      out[64 + b] = (float)f0;            // size
    }
  }
}

extern "C" void kernel_launch(void* const* d_in, const int* in_sizes, int n_in,
                              void* d_out, int out_size, void* d_ws, size_t ws_size,
                              hipStream_t stream) {
  const float* cal_feat = (const float*)d_in[0];
  const float* test_feat = (const float*)d_in[1];
  const int* cal_gt = (const int*)d_in[2];
  const int* test_gt = (const int*)d_in[3];
  float* out = (float*)d_out;
  char* ws = (char*)d_ws;

  float* test_res = (float*)(ws + OFF_TESTRES);
  unsigned short* cal_bf = (unsigned short*)(ws + OFF_CALBF);
  unsigned short* test_bf = (unsigned short*)(ws + OFF_TESTBF);
  unsigned short* grouped = (unsigned short*)(ws + OFF_GROUPED);
  unsigned short* cdf = (unsigned short*)(ws + OFF_CDF);
  unsigned short* cdfT = (unsigned short*)(ws + OFF_CDFT);
  float* gpart = (float*)(ws + OFF_GPART);
  float* cc = (float*)(ws + OFF_CC);
  float* thr = (float*)(ws + OFF_THR);
  float* lam = (float*)(ws + OFF_LAM);
  int* facc = (int*)(ws + OFF_FACC);

  k_calt<<<dim3(256), dim3(1024), 0, stream>>>(cal_feat, cal_gt, cal_bf, cdf, grouped, cc,
                                               test_feat, test_res, test_bf);
  k_gemmtr<<<dim3(8, 80), dim3(256), 0, stream>>>(test_bf, cal_bf, gpart, cdf, cdfT);
  k_quantw<<<dim3(32), dim3(512), 0, stream>>>(gpart, cc, test_bf, cdf, cdfT, grouped,
                                               lam, thr, facc);
  k_finalp<<<dim3(32, 8), dim3(256), 0, stream>>>(test_res, test_gt, thr, lam, facc, out);
}

// Round 10
// 225.929 us; speedup vs baseline: 1.2093x; 1.0051x over previous
//
#include <hip/hip_runtime.h>

// RandomlyLocalizedConformalRiskControl on MI355X.
// ws layout (bytes), total ~98.4 MB:
//   test_res f32 [32][65536]             @ 0          (8 MB)    f32 scores for final scan
//   cal_bf   u16 [256][65536]            @ 8388608    (32 MB)   bf16 cal scores (MFMA A/B)
//   test_bf  u16 [32][65536]             @ 41943040   (4 MB)    bf16 test scores
//   grouped  u16 [256][65536]            @ 46137344   (32 MB)   low-16 bits of f32 score, grouped by hi-16 bucket
//   cdf      u16 [256][CDF_STRIDE]       @ 79691776   (8.3 MB)  exclusive CDF, row-major (gather/pos)
//   gpart    f32 [64][8][1024]           @ 88023040   (2 MB)    split-K MFMA partials (deterministic)
//   cc f32[256], thr f32[32], lam f32[32], facc i32[32][4]
//   cdfT     u16 [16256][256]            @ 90122240   (8.3 MB)  TRANSPOSED cdf: coalesced binary search
// Pipeline (4 launches): k_calt -> k_gemmtr (GEMM y<64 + 128-block transpose y>=64)
// -> k_quantw -> k_finalp (absorbs k_out).
// R10 = R8's k_calt (launch_bounds (1024,2): 67 us measured; (1024,1) kept VGPR=64 AND
// halved throughput via degraded scheduling — R9 lesson) + R9's parallel-transpose rest
// (rest = 104.6 us measured).

#define NPIX 65536
#define HB 16256            // buckets = float_bits >> 16 for scores in (0, 1.0]
#define CDF_STRIDE 16272
#define ALPHA 0.1f
#define STAGE_CAP 35840     // u16 staging entries; pos ~ Bin(65536,1/2) max ~33.4K (+24 sigma)

#define OFF_TESTRES  0
#define OFF_CALBF    8388608u
#define OFF_TESTBF   41943040u
#define OFF_GROUPED  46137344u
#define OFF_CDF      79691776u
#define OFF_GPART    88023040u
#define OFF_CC       90120192u
#define OFF_THR      90121216u
#define OFF_LAM      90121344u
#define OFF_FACC     90121472u
#define OFF_CDFT     90122240u

typedef __attribute__((ext_vector_type(8))) short bf16x8;
typedef __attribute__((ext_vector_type(16))) float f32x16;

__device__ __forceinline__ unsigned f2bf_rne(float f) {
  unsigned u = __float_as_uint(f);
  return (u + 0x7FFFu + ((u >> 16) & 1u)) >> 16;
}

// XOR swizzle on bucket index: involution, closed within each 32-word block.
__device__ __forceinline__ int SW(int w) { return w ^ ((w >> 5) & 31); }

// The sigmoid tail shared by ALL score evaluation sites: identical inlined expression
// tree -> identical FMA contraction -> bit-identical f32 on every recompute/reuse.
__device__ __forceinline__ float sig_v(float a, float b, float wy) {
  float v = a * (1.f - wy) + b * wy;
  return 1.f / (1.f + __expf(-v));
}

// Row x-interp for the 4 pixels of a thread's patch: SAME source expression shape as
// the original score_at row interp (f[x0]*(1-wx) + f[x1]*wx with runtime wx), operands
// pre-selected per-k (cL/cM/cR reproduce the clamped x0/x1 pairs exactly, including
// the x=0 / x=255 both-operands-equal corner cases).
#define ROWH(F, r, h0, h1, h2, h3)                                        \
  {                                                                       \
    float fL_ = (F)[(r) * 64 + cL];                                       \
    float fM_ = (F)[(r) * 64 + cM];                                       \
    float fR_ = (F)[(r) * 64 + cR];                                       \
    h0 = fL_ * (1.f - wx0) + fM_ * wx0;                                   \
    h1 = fL_ * (1.f - wx1) + fM_ * wx1;                                   \
    h2 = fM_ * (1.f - wx2) + fR_ * wx2;                                   \
    h3 = fM_ * (1.f - wx3) + fR_ * wx3;                                   \
  }

// ---- fused cal+test features, 256 blocks (one per cal sample) ----
// 4-pixel-wide patches (R8): thread (xg, band) owns x=4xg..4xg+3, rows [16*band,+16).
// __launch_bounds__(1024, 2): measured-best config (67 us). The VGPR=64 cap spills
// (~+35 MB scratch traffic) but runs 2x faster than (1024,1), which kept VGPR=64 AND
// collapsed VALUBusy 48->27% (scheduler optimized for 1-wave residency). Do not "fix".
// smem map (u32): [0,16256) hist -> CDF -> scatter counters (swizzled); [16256,16272)
// scan wave totals; [16272,16288) cc partials; [16288,17312) thread prefixes; [17312] pos.
__global__ __launch_bounds__(1024, 2) void k_calt(const float* __restrict__ featc,
                                                  const int* __restrict__ gt,
                                                  unsigned short* __restrict__ calbf,
                                                  unsigned short* __restrict__ cdf,
                                                  unsigned short* __restrict__ grouped,
                                                  float* __restrict__ cc,
                                                  const float* __restrict__ featt,
                                                  float* __restrict__ tres,
                                                  unsigned short* __restrict__ tbf) {
  __shared__ unsigned smem[17313];
  __shared__ float sfeat[4096];
  __shared__ __align__(16) unsigned short sstage[STAGE_CAP];
  float* tfeat = (float*)sstage;                    // sstage[0..8191]: dead before phase B
  unsigned* gmask = (unsigned*)(sstage + 8192);     // sstage[8192..12287]: dead before phase B
  const int tid = threadIdx.x;
  const int lane = tid & 63, wv = tid >> 6;
  const int xg = tid & 63, band = tid >> 6;  // patch col group / 16-row band
  // per-k x-interp params: identical per-pixel computation as before (x = 4*xg + k)
  float wx0, wx1, wx2, wx3;
  {
    float sx0 = 0.25f * (float)(4 * xg + 0) - 0.375f;
    float sx1 = 0.25f * (float)(4 * xg + 1) - 0.375f;
    float sx2 = 0.25f * (float)(4 * xg + 2) - 0.375f;
    float sx3 = 0.25f * (float)(4 * xg + 3) - 0.375f;
    wx0 = sx0 - (float)((int)floorf(sx0));
    wx1 = sx1 - (float)((int)floorf(sx1));
    wx2 = sx2 - (float)((int)floorf(sx2));
    wx3 = sx3 - (float)((int)floorf(sx3));
  }
  const int cL = (xg == 0) ? 0 : xg - 1;
  const int cM = xg;
  const int cR = (xg == 63) ? 63 : xg + 1;

  const int n = blockIdx.x;
  const int b = n >> 3, sl = n & 7;  // test sample + slice handled by this block
  for (int i = tid; i < HB; i += 1024) smem[i] = 0;
  for (int i = tid; i < 4096; i += 1024) {
    sfeat[i] = featc[n * 4096 + i];
    tfeat[i] = featt[b * 4096 + i];
  }
  // gt bitmask pre-pass: coalesced int4 loads -> 8 KB LDS bitmask
  {
    const int4* gt4 = (const int4*)(gt + (size_t)n * NPIX);
    for (int w = tid; w < 2048; w += 1024) {
      unsigned m = 0;
      #pragma unroll
      for (int j = 0; j < 8; ++j) {
        int4 g = gt4[w * 8 + j];
        m |= (g.x > 0 ? 1u : 0u) << (j * 4);
        m |= (g.y > 0 ? 2u : 0u) << (j * 4);
        m |= (g.z > 0 ? 4u : 0u) << (j * 4);
        m |= (g.w > 0 ? 8u : 0u) << (j * 4);
      }
      gmask[w] = m;
    }
  }
  unsigned short* cbn = calbf + (size_t)n * NPIX;
  __syncthreads();  // S0: feats + hist + gmask ready

  // ---- test slice: rows {sl*32+2*band, +1} x cols 4xg..4xg+3 (one quad window) ----
  {
    const int tr0 = sl * 32 + 2 * band;
    const int mt = tr0 >> 2, j0 = tr0 & 3;  // quad, first row-in-quad (0 or 2)
    float tp0, tp1, tp2, tp3, tc0, tc1, tc2, tc3, tn0, tn1, tn2, tn3;
    int rp = (mt == 0) ? 0 : mt - 1;
    int rn = (mt == 63) ? 63 : mt + 1;
    ROWH(tfeat, rp, tp0, tp1, tp2, tp3);
    ROWH(tfeat, mt, tc0, tc1, tc2, tc3);
    ROWH(tfeat, rn, tn0, tn1, tn2, tn3);
    float* resb = tres + (size_t)b * NPIX;
    unsigned short* tbn = tbf + (size_t)b * NPIX;
    #pragma unroll
    for (int jj = 0; jj < 2; ++jj) {
      int j = j0 + jj;
      int y = 4 * mt + j;
      float sy = 0.25f * (float)y - 0.375f;
      int y0i = (int)floorf(sy);
      float wy = sy - (float)y0i;
      float a0 = j < 2 ? tp0 : tc0, b0 = j < 2 ? tc0 : tn0;
      float a1 = j < 2 ? tp1 : tc1, b1 = j < 2 ? tc1 : tn1;
      float a2 = j < 2 ? tp2 : tc2, b2 = j < 2 ? tc2 : tn2;
      float a3 = j < 2 ? tp3 : tc3, b3 = j < 2 ? tc3 : tn3;
      float s0 = sig_v(a0, b0, wy), s1 = sig_v(a1, b1, wy);
      float s2 = sig_v(a2, b2, wy), s3 = sig_v(a3, b3, wy);
      float4 rv = {s0, s1, s2, s3};
      *(float4*)(resb + (y << 8) + 4 * xg) = rv;
      uint2 pk;
      pk.x = f2bf_rne(s0) | (f2bf_rne(s1) << 16);
      pk.y = f2bf_rne(s2) | (f2bf_rne(s3) << 16);
      *(uint2*)(tbn + (y << 8) + 4 * xg) = pk;
    }
  }

  // ---- cal phase A: 4-wide patch scores, packed stores, bitmask, hist, cc ----
  const int mq0 = band * 4;  // quads mq0..mq0+3 (rows 16*band..+15)
  unsigned long long pm = 0ull;
  float sumsq = 0.f;
  {
    float hp0, hp1, hp2, hp3, hc0, hc1, hc2, hc3, hn0, hn1, hn2, hn3;
    int rp = (mq0 == 0) ? 0 : mq0 - 1;
    ROWH(sfeat, rp, hp0, hp1, hp2, hp3);
    ROWH(sfeat, mq0, hc0, hc1, hc2, hc3);
    for (int qq = 0; qq < 4; ++qq) {
      int m = mq0 + qq;
      int rn = (m == 63) ? 63 : m + 1;
      ROWH(sfeat, rn, hn0, hn1, hn2, hn3);
      #pragma unroll
      for (int j = 0; j < 4; ++j) {
        int y = 4 * m + j;
        float sy = 0.25f * (float)y - 0.375f;
        int y0i = (int)floorf(sy);
        float wy = sy - (float)y0i;
        float a0 = j < 2 ? hp0 : hc0, b0 = j < 2 ? hc0 : hn0;
        float a1 = j < 2 ? hp1 : hc1, b1 = j < 2 ? hc1 : hn1;
        float a2 = j < 2 ? hp2 : hc2, b2 = j < 2 ? hc2 : hn2;
        float a3 = j < 2 ? hp3 : hc3, b3 = j < 2 ? hc3 : hn3;
        float s0 = sig_v(a0, b0, wy), s1 = sig_v(a1, b1, wy);
        float s2 = sig_v(a2, b2, wy), s3 = sig_v(a3, b3, wy);
        unsigned u0 = f2bf_rne(s0), u1 = f2bf_rne(s1);
        unsigned u2 = f2bf_rne(s2), u3 = f2bf_rne(s3);
        uint2 pk;
        pk.x = u0 | (u1 << 16);
        pk.y = u2 | (u3 << 16);
        *(uint2*)(cbn + (y << 8) + 4 * xg) = pk;
        float r0 = __uint_as_float(u0 << 16), r1 = __uint_as_float(u1 << 16);
        float r2 = __uint_as_float(u2 << 16), r3 = __uint_as_float(u3 << 16);
        sumsq += r0 * r0;
        sumsq += r1 * r1;
        sumsq += r2 * r2;
        sumsq += r3 * r3;
        unsigned nib = (gmask[(y << 3) + (xg >> 3)] >> (4 * (xg & 7))) & 0xFu;
        if (nib & 1u) {
          pm |= 1ull << (qq * 16 + j * 4 + 0);
          atomicAdd(&smem[SW((int)(__float_as_uint(s0) >> 16))], 1u);
        }
        if (nib & 2u) {
          pm |= 1ull << (qq * 16 + j * 4 + 1);
          atomicAdd(&smem[SW((int)(__float_as_uint(s1) >> 16))], 1u);
        }
        if (nib & 4u) {
          pm |= 1ull << (qq * 16 + j * 4 + 2);
          atomicAdd(&smem[SW((int)(__float_as_uint(s2) >> 16))], 1u);
        }
        if (nib & 8u) {
          pm |= 1ull << (qq * 16 + j * 4 + 3);
          atomicAdd(&smem[SW((int)(__float_as_uint(s3) >> 16))], 1u);
        }
      }
      hp0 = hc0; hp1 = hc1; hp2 = hc2; hp3 = hc3;
      hc0 = hn0; hc1 = hn1; hc2 = hn2; hc3 = hn3;
    }
  }
  // cc partials (16 waves); band-patch accumulation order (reassociation accepted)
  #pragma unroll
  for (int off = 32; off; off >>= 1) sumsq += __shfl_xor(sumsq, off);
  if (lane == 0) smem[16272 + wv] = __float_as_uint(sumsq);
  __syncthreads();  // S1: hist + cc partials final
  if (tid == 0) {
    float c = 0.f;
    for (int w = 0; w < 16; ++w) c += __uint_as_float(smem[16272 + w]);
    cc[n] = c;
  }
  // ---- exclusive scan: threads 0..1015, 16 buckets each ----
  const int base = tid * 16;
  unsigned psum = 0;
  if (tid < 1016) {
    #pragma unroll
    for (int j = 0; j < 16; ++j) psum += smem[SW(base + j)];
  }
  unsigned inc = psum;
  #pragma unroll
  for (int off = 1; off < 64; off <<= 1) {
    unsigned v = __shfl_up(inc, off);
    if (lane >= off) inc += v;
  }
  if (lane == 63) smem[16256 + wv] = inc;  // wave totals
  smem[16288 + tid] = inc - psum;          // thread-exclusive prefix within wave
  __syncthreads();  // S2: totals + prefixes ready
  {
    unsigned woff = 0;
    for (int w = 0; w < wv; ++w) woff += smem[16256 + w];  // broadcast reads
    unsigned run = woff + smem[16288 + tid];
    if (tid < 1016) {
      #pragma unroll
      for (int j = 0; j < 16; ++j) {
        int si = SW(base + j);
        unsigned h = smem[si];
        smem[si] = run;  // exclusive CDF -> scatter counters
        run += h;
      }
    }
    if (tid == 1015) smem[17312] = run;  // total positives (lanes above 1015 hold 0)
  }
  __syncthreads();  // S2b: counters final
  // ---- COALESCED u16 cdf copyout ----
  unsigned short* cdfn = cdf + (size_t)n * CDF_STRIDE;
  for (int i = tid; i < HB; i += 1024) cdfn[i] = (unsigned short)smem[SW(i)];
  const unsigned pos = smem[17312];
  if (tid == 0) cdfn[HB] = (unsigned short)pos;  // pos < 2^16 for Bin(65536,1/2) data
  __syncthreads();  // S3: cdf written before counters mutate
  // ---- phase B: patch recompute (bit-exact expression reuse), LDS staging ----
  unsigned short* gn = grouped + (size_t)n * NPIX;
  {
    float hp0, hp1, hp2, hp3, hc0, hc1, hc2, hc3, hn0, hn1, hn2, hn3;
    int rp = (mq0 == 0) ? 0 : mq0 - 1;
    ROWH(sfeat, rp, hp0, hp1, hp2, hp3);
    ROWH(sfeat, mq0, hc0, hc1, hc2, hc3);
    for (int qq = 0; qq < 4; ++qq) {
      int m = mq0 + qq;
      int rn = (m == 63) ? 63 : m + 1;
      ROWH(sfeat, rn, hn0, hn1, hn2, hn3);
      unsigned qb = (unsigned)(pm >> (qq * 16)) & 0xFFFFu;
      if (qb) {
        #pragma unroll
        for (int j = 0; j < 4; ++j) {
          unsigned nib = (qb >> (j * 4)) & 0xFu;
          if (nib) {
            int y = 4 * m + j;
            float sy = 0.25f * (float)y - 0.375f;
            int y0i = (int)floorf(sy);
            float wy = sy - (float)y0i;
            float a0 = j < 2 ? hp0 : hc0, b0 = j < 2 ? hc0 : hn0;
            float a1 = j < 2 ? hp1 : hc1, b1 = j < 2 ? hc1 : hn1;
            float a2 = j < 2 ? hp2 : hc2, b2 = j < 2 ? hc2 : hn2;
            float a3 = j < 2 ? hp3 : hc3, b3 = j < 2 ? hc3 : hn3;
            #pragma unroll
            for (int k = 0; k < 4; ++k) {
              if (nib & (1u << k)) {
                float s = k == 0 ? sig_v(a0, b0, wy)
                        : k == 1 ? sig_v(a1, b1, wy)
                        : k == 2 ? sig_v(a2, b2, wy)
                                 : sig_v(a3, b3, wy);
                unsigned bits = __float_as_uint(s);
                unsigned idx = atomicAdd(&smem[SW((int)(bits >> 16))], 1u);
                unsigned short lo = (unsigned short)(bits & 0xFFFFu);
                if (idx < STAGE_CAP) sstage[idx] = lo;
                else gn[idx] = lo;  // overflow fallback: same final location
              }
            }
          }
        }
      }
      hp0 = hc0; hp1 = hc1; hp2 = hc2; hp3 = hc3;
      hc0 = hn0; hc1 = hn1; hc2 = hn2; hc3 = hn3;
    }
  }
  __syncthreads();  // S4: staging complete
  // ---- COALESCED grouped copyout ----
  unsigned lim = pos < STAGE_CAP ? pos : STAGE_CAP;
  for (unsigned i = tid; i < lim; i += 1024) gn[i] = sstage[i];
}

// ---- merged GEMM + cdf transpose; grid (8, 80): y<64 GEMM, y>=64 transpose ----
// GEMM: gpart[ks][nt][m*32+nl] = <test_m, cal_(nt*32+nl)>, LDS-staged, XOR-swizzled,
// 32x32x16 bf16 MFMA, wave = K-quarter split, cross-wave reduce in lred.
// Transpose: 128 blocks, ONE 128-bucket tile each (R8's 8-block version serialized the
// latency-bound uncoalesced read side 16x -> +65 us; R9's 128-block version measured
// rest = 104.6 us — keep). cdfT[bucket][n] = cdf[n][bucket], bit-exact search input.
__global__ __launch_bounds__(256) void k_gemmtr(const unsigned short* __restrict__ tbf,
                                                const unsigned short* __restrict__ cbf,
                                                float* __restrict__ gpart,
                                                const unsigned short* __restrict__ cdf,
                                                unsigned short* __restrict__ cdfT) {
  __shared__ __align__(16) char lds[81920];
  const int tid = threadIdx.x;
  if (blockIdx.y >= 64) {
    // ---- transpose role: tile t = (y-64)*8 + x in [0,127) ----
    const int t = (blockIdx.y - 64) * 8 + blockIdx.x;
    if (t >= 127) return;
    unsigned short (*tile)[136] = (unsigned short (*)[136])lds;  // 16B-aligned rows
    const int b0 = t * 128;
    const unsigned short* src = cdf + (size_t)tid * CDF_STRIDE + b0;
    #pragma unroll
    for (int j = 0; j < 128; j += 8)
      *(int4*)&tile[tid][j] = *(const int4*)(src + j);
    __syncthreads();
    for (int j = 0; j < 128; ++j)
      cdfT[(size_t)(b0 + j) * 256 + tid] = tile[tid][j];
    return;
  }
  // ---- GEMM role ----
  unsigned short* As = (unsigned short*)lds;            // 32 KB
  unsigned short* Bs = (unsigned short*)(lds + 32768);  // 32 KB
  float (*lred)[1024] = (float (*)[1024])(lds + 65536); // 16 KB
  const int lane = tid & 63, wv = tid >> 6;
  const int r = lane & 31, half = lane >> 5;
  const int nt = blockIdx.x;              // 0..7: cal column tile
  f32x16 acc;
  #pragma unroll
  for (int i = 0; i < 16; ++i) acc[i] = 0.f;
  for (int ch = 0; ch < 2; ++ch) {        // two 512-K chunks of this block's 1024-K slice
    const size_t kbase = (size_t)blockIdx.y * 1024 + ch * 512;
    __syncthreads();
    #pragma unroll
    for (int s = 0; s < 16; ++s) {
      int flat = s * 256 + tid;           // 0..4095; <2048 = A, else B (wave-uniform per s)
      int rem = flat & 2047;
      int row = rem >> 6, kb = rem & 63;
      const unsigned short* src = (flat >= 2048)
          ? cbf + (size_t)(nt * 32 + row) * NPIX + kbase + kb * 8
          : tbf + (size_t)row * NPIX + kbase + kb * 8;
      int slot = ((kb << 5) + row) ^ (kb & 31);   // XOR swizzle breaks write-bank collisions
      int4 v = *(const int4*)src;
      *(int4*)((flat >= 2048 ? Bs : As) + slot * 8) = v;
    }
    __syncthreads();
    #pragma unroll
    for (int i = 0; i < 8; ++i) {         // wave's K-quarter: kblk in [wv*16, wv*16+16)
      int k8 = (wv << 4) + i * 2 + half;
      int slot = ((k8 << 5) + r) ^ (k8 & 31);
      bf16x8 a = *(const bf16x8*)(As + slot * 8);
      bf16x8 b = *(const bf16x8*)(Bs + slot * 8);
      acc = __builtin_amdgcn_mfma_f32_32x32x16_bf16(a, b, acc, 0, 0, 0);
    }
  }
  // C/D layout (HW-verified): col = lane&31, row = (reg&3) + 8*(reg>>2) + 4*(lane>>5)
  #pragma unroll
  for (int rg = 0; rg < 16; ++rg) {
    int m = (rg & 3) + 8 * (rg >> 2) + 4 * half;
    lred[wv][m * 32 + r] = acc[rg];
  }
  __syncthreads();
  float* gp = gpart + (size_t)(blockIdx.y * 8 + nt) * 1024;
  for (int e = tid; e < 1024; e += 256)
    gp[e] = lred[0][e] + lred[1][e] + lred[2][e] + lred[3][e];
}

// ---- tt + weights + weighted-quantile; zero-inits facc; writes thr/lam ----
__global__ __launch_bounds__(512) void k_quantw(const float* __restrict__ gpart,
                                                const float* __restrict__ cc,
                                                const unsigned short* __restrict__ tbf,
                                                const unsigned short* __restrict__ cdf,
                                                const unsigned short* __restrict__ cdfT,
                                                const unsigned short* __restrict__ grouped,
                                                float* __restrict__ lam,
                                                float* __restrict__ thr,
                                                int* __restrict__ facc) {
  __shared__ float qs[256];
  __shared__ float bins[4096];
  __shared__ float red[8];
  __shared__ float tpart[16];
  __shared__ float bc[3];      // [0]=wsum [1]=S(mid) [2]=tt
  __shared__ unsigned sBin;
  const int b = blockIdx.x, tid = threadIdx.x;
  const int lane = tid & 63, wv = tid >> 6;

  if (tid < 4) facc[b * 4 + tid] = 0;
  for (int i = tid; i < 4096; i += 512) bins[i] = 0.f;
  if (tid == 0) sBin = 0xFFFFFFFFu;

  // ---- tt[b]: bit-exact virtual-thread replica of the original 1024-thread reduction ----
  {
    const unsigned short* tbn = tbf + (size_t)b * NPIX;
    const int xa = tid & 255, ya = tid >> 8;        // virtual thread vt = tid
    const int yb = ya + 2;                          // virtual thread vt = tid + 512
    float sa = 0.f, sb = 0.f;
    #pragma unroll 4
    for (int it = 0; it < 64; ++it) {
      float ra = __uint_as_float((unsigned)tbn[((it * 4 + ya) << 8) + xa] << 16);
      float rb = __uint_as_float((unsigned)tbn[((it * 4 + yb) << 8) + xa] << 16);
      sa += ra * ra;
      sb += rb * rb;
    }
    #pragma unroll
    for (int off = 32; off; off >>= 1) {
      sa += __shfl_xor(sa, off);
      sb += __shfl_xor(sb, off);
    }
    if (lane == 0) { tpart[wv] = sa; tpart[8 + wv] = sb; }
  }
  __syncthreads();
  if (tid == 0) {
    float t = 0.f;
    for (int w = 0; w < 16; ++w) t += tpart[w];
    bc[2] = t;
  }
  // ---- weights g-sum (independent of tt) ----
  float g = 0.f;
  if (tid < 256) {
    const float* gp = gpart + ((tid >> 5) * 1024) + (b * 32) + (tid & 31);
    #pragma unroll 8
    for (int ks = 0; ks < 64; ++ks) g += gp[(size_t)ks * 8192];
  }
  __syncthreads();  // bc[2] visible
  float k = 0.f;
  if (tid < 256) {
    float d2 = bc[2] + cc[tid] - 2.f * g;
    k = expf(-d2 * (1.f / 8192.f));
  }
  float v = k;
  #pragma unroll
  for (int off = 32; off; off >>= 1) v += __shfl_xor(v, off);
  if (lane == 0) red[wv] = v;
  __syncthreads();
  if (tid == 0) {
    float ws = 1.f;
    for (int w = 0; w < 8; ++w) ws += red[w];
    bc[0] = ws;
  }
  __syncthreads();
  const float wsum = bc[0];
  const float wlast = 1.f / wsum;
  const float R = ALPHA - wlast;
  if (R <= 0.f) {  // risk >= alpha for every lam -> low -> 1.0f, thr 0 (predict all)
    if (tid == 0) { lam[b] = 1.0f; thr[b] = 0.0f; }
    return;
  }
  if (tid < 256) {
    unsigned pos = cdf[(size_t)tid * CDF_STRIDE + HB];
    qs[tid] = k / (wsum * (float)(pos ? pos : 1u));
  }
  __syncthreads();

  // ---- 14-step binary search over hi-16 buckets (coalesced via cdfT) ----
  int lo = 0, hi = HB;
  float baseS = 0.f;
  for (int it = 0; it < 14; ++it) {
    int mid = (lo + hi) >> 1;
    float p = 0.f;
    if (tid < 256) p = qs[tid] * (float)cdfT[(size_t)mid * 256 + tid];
    float r = p;
    #pragma unroll
    for (int off = 32; off; off >>= 1) r += __shfl_xor(r, off);
    if (lane == 0) red[wv] = r;
    __syncthreads();
    if (tid == 0) {
      float s = 0.f;
      for (int w = 0; w < 8; ++w) s += red[w];
      bc[1] = s;
    }
    __syncthreads();
    float S = bc[1];
    if (S < R) { lo = mid; baseS = S; } else { hi = mid; }
  }
  const int B = lo;  // crossing bucket; baseS = weighted count below it

  // ---- gather bucket B members into 4096-bin weighted histogram of lo16>>4 ----
  {
    const int n = tid >> 1;
    const float q = qs[n];
    const unsigned short* cn = cdf + (size_t)n * CDF_STRIDE;
    const unsigned short* gn = grouped + (size_t)n * NPIX;
    unsigned e0 = cn[B + 1];
    for (unsigned j = (unsigned)cn[B] + (tid & 1); j < e0; j += 2)
      atomicAdd(&bins[gn[j] >> 4], q);
  }
  __syncthreads();

  // ---- wave 0: scan 4096 bins, find crossing bin ----
  if (wv == 0) {
    float s = 0.f;
    for (int j = 0; j < 64; ++j) s += bins[lane * 64 + j];
    float inc = s;
    #pragma unroll
    for (int off = 1; off < 64; off <<= 1) {
      float u = __shfl_up(inc, off);
      if (lane >= off) inc += u;
    }
    float pre = inc - s;
    bool hit = (baseS + pre < R) && (baseS + inc >= R);
    unsigned long long m = __ballot(hit);
    int ow = m ? (__ffsll((unsigned long long)m) - 1) : -1;
    if (lane == ow) {
      float run = baseS + pre;
      unsigned bin = (unsigned)lane * 64 + 63;
      for (int j = 0; j < 64; ++j) {
        float bv = bins[lane * 64 + j];
        if (run + bv >= R) { bin = (unsigned)lane * 64 + j; break; }
        run += bv;
      }
      sBin = bin;
    }
    if (m == 0 && lane == 0) sBin = 4095u;  // f32-rounding fallback (unreachable in practice)
  }
  __syncthreads();
  if (tid == 0) {
    unsigned tb = ((unsigned)B << 16) | (sBin << 4);
    lam[b] = 1.0f - __uint_as_float(tb | 0x8u);     // mid-bin representative
    thr[b] = __uint_as_float((tb | 0xFu) + 1u);     // strictly above bin top: pred = res > u*
  }
}

// ---- final partials + output: grid (32 samples, 8 segments) ----
// Absorbs k_out: the 8th-arriving segment block per sample reads the device-scope
// accumulated counts and writes out[] directly (saves a launch).
__global__ __launch_bounds__(256) void k_finalp(const float* __restrict__ tres,
                                                const int* __restrict__ tgt,
                                                const float* __restrict__ thr,
                                                const float* __restrict__ lam,
                                                int* __restrict__ facc,
                                                float* __restrict__ out) {
  __shared__ int red[12];
  const int b = blockIdx.x, seg = blockIdx.y, tid = threadIdx.x;
  const int lane = tid & 63, wv = tid >> 6;
  const float th = thr[b];
  const float4* rb4 = (const float4*)(tres + (size_t)b * NPIX + seg * 8192);
  const int4* gb4 = (const int4*)(tgt + (size_t)b * NPIX + seg * 8192);
  int sz = 0, tp = 0, tpos = 0;
  #pragma unroll
  for (int i = 0; i < 8; ++i) {
    float4 r4 = rb4[i * 256 + tid];
    int4 g4 = gb4[i * 256 + tid];
    int p0 = (r4.x >= th), t0 = (g4.x > 0);
    int p1 = (r4.y >= th), t1 = (g4.y > 0);
    int p2 = (r4.z >= th), t2 = (g4.z > 0);
    int p3 = (r4.w >= th), t3 = (g4.w > 0);
    sz += p0 + p1 + p2 + p3;
    tp += (p0 & t0) + (p1 & t1) + (p2 & t2) + (p3 & t3);
    tpos += t0 + t1 + t2 + t3;
  }
  #pragma unroll
  for (int off = 32; off; off >>= 1) {
    sz += __shfl_xor(sz, off);
    tp += __shfl_xor(tp, off);
    tpos += __shfl_xor(tpos, off);
  }
  if (lane == 0) { red[wv] = sz; red[4 + wv] = tp; red[8 + wv] = tpos; }
  __syncthreads();
  if (tid == 0) {
    int s0 = red[0] + red[1] + red[2] + red[3];
    int s1 = red[4] + red[5] + red[6] + red[7];
    int s2 = red[8] + red[9] + red[10] + red[11];
    atomicAdd(&facc[b * 4 + 0], s0);
    atomicAdd(&facc[b * 4 + 1], s1);
    atomicAdd(&facc[b * 4 + 2], s2);
    __threadfence();  // publish before arrival
    int done = atomicAdd(&facc[b * 4 + 3], 1);
    if (done == 7) {  // last of 8 segment blocks: all adds are visible via atomics
      int f0 = atomicAdd(&facc[b * 4 + 0], 0);
      int f1 = atomicAdd(&facc[b * 4 + 1], 0);
      int f2 = atomicAdd(&facc[b * 4 + 2], 0);
      float tposf = (float)(f2 > 0 ? f2 : 1);
      out[b] = 1.f - (float)f1 / tposf;   // fnr_test
      out[32 + b] = lam[b];               // lambda
      out[64 + b] = (float)f0;            // size
    }
  }
}

extern "C" void kernel_launch(void* const* d_in, const int* in_sizes, int n_in,
                              void* d_out, int out_size, void* d_ws, size_t ws_size,
                              hipStream_t stream) {
  const float* cal_feat = (const float*)d_in[0];
  const float* test_feat = (const float*)d_in[1];
  const int* cal_gt = (const int*)d_in[2];
  const int* test_gt = (const int*)d_in[3];
  float* out = (float*)d_out;
  char* ws = (char*)d_ws;

  float* test_res = (float*)(ws + OFF_TESTRES);
  unsigned short* cal_bf = (unsigned short*)(ws + OFF_CALBF);
  unsigned short* test_bf = (unsigned short*)(ws + OFF_TESTBF);
  unsigned short* grouped = (unsigned short*)(ws + OFF_GROUPED);
  unsigned short* cdf = (unsigned short*)(ws + OFF_CDF);
  unsigned short* cdfT = (unsigned short*)(ws + OFF_CDFT);
  float* gpart = (float*)(ws + OFF_GPART);
  float* cc = (float*)(ws + OFF_CC);
  float* thr = (float*)(ws + OFF_THR);
  float* lam = (float*)(ws + OFF_LAM);
  int* facc = (int*)(ws + OFF_FACC);

  k_calt<<<dim3(256), dim3(1024), 0, stream>>>(cal_feat, cal_gt, cal_bf, cdf, grouped, cc,
                                               test_feat, test_res, test_bf);
  k_gemmtr<<<dim3(8, 80), dim3(256), 0, stream>>>(test_bf, cal_bf, gpart, cdf, cdfT);
  k_quantw<<<dim3(32), dim3(512), 0, stream>>>(gpart, cc, test_bf, cdf, cdfT, grouped,
                                               lam, thr, facc);
  k_finalp<<<dim3(32, 8), dim3(256), 0, stream>>>(test_res, test_gt, thr, lam, facc, out);
}

// Round 11
// 220.119 us; speedup vs baseline: 1.2412x; 1.0264x over previous
//
#include <hip/hip_runtime.h>

// RandomlyLocalizedConformalRiskControl on MI355X.
// ws layout (bytes), total ~98.4 MB:
//   test_res f32 [32][65536]             @ 0          (8 MB)    f32 scores for final scan
//   cal_bf   u16 [256][65536]            @ 8388608    (32 MB)   bf16 cal scores (MFMA A/B)
//   test_bf  u16 [32][65536]             @ 41943040   (4 MB)    bf16 test scores
//   grouped  u16 [256][65536]            @ 46137344   (32 MB)   low-16 bits of f32 score, grouped by hi-16 bucket
//   cdf      u16 [256][CDF_STRIDE]       @ 79691776   (8.3 MB)  exclusive CDF, row-major (gather/pos)
//   gpart    f32 [64][8][1024]           @ 88023040   (2 MB)    split-K MFMA partials (deterministic)
//   cc f32[256], thr f32[32], lam f32[32], facc i32[32][4]
//   cdfT     u16 [16256][256]            @ 90122240   (8.3 MB)  TRANSPOSED cdf: coalesced binary search
// Pipeline (4 launches): k_calt -> k_gemmtr (GEMM y<64 + 128-block transpose y>=64)
// -> k_quantw -> k_finalp (absorbs k_out).
// R11: k_calt patches narrowed 4-wide -> 2-wide. A 2-aligned pixel pair shares one
// (x0,x1) feature-column pair, so live state halves (2 cols + 2 wx + 6-reg rolling
// window) and fits the (1024,2) VGPR=64 cap WITHOUT the ~35 MB scratch round-trip
// R8/R10 paid. (1024,2) kept: it is the measured-fast schedule (R9: (1024,1) same
// VGPR, half the throughput).

#define NPIX 65536
#define HB 16256            // buckets = float_bits >> 16 for scores in (0, 1.0]
#define CDF_STRIDE 16272
#define ALPHA 0.1f
#define STAGE_CAP 35840     // u16 staging entries; pos ~ Bin(65536,1/2) max ~33.4K (+24 sigma)

#define OFF_TESTRES  0
#define OFF_CALBF    8388608u
#define OFF_TESTBF   41943040u
#define OFF_GROUPED  46137344u
#define OFF_CDF      79691776u
#define OFF_GPART    88023040u
#define OFF_CC       90120192u
#define OFF_THR      90121216u
#define OFF_LAM      90121344u
#define OFF_FACC     90121472u
#define OFF_CDFT     90122240u

typedef __attribute__((ext_vector_type(8))) short bf16x8;
typedef __attribute__((ext_vector_type(16))) float f32x16;

__device__ __forceinline__ unsigned f2bf_rne(float f) {
  unsigned u = __float_as_uint(f);
  return (u + 0x7FFFu + ((u >> 16) & 1u)) >> 16;
}

// XOR swizzle on bucket index: involution, closed within each 32-word block.
__device__ __forceinline__ int SW(int w) { return w ^ ((w >> 5) & 31); }

// The sigmoid tail shared by ALL score evaluation sites: identical inlined expression
// tree -> identical FMA contraction -> bit-identical f32 on every recompute/reuse.
__device__ __forceinline__ float sig_v(float a, float b, float wy) {
  float v = a * (1.f - wy) + b * wy;
  return 1.f / (1.f + __expf(-v));
}

// Row x-interp for the 2 pixels of a thread's patch: SAME source expression as the
// original score_at row interp (f[x0]*(1-wx) + f[x1]*wx, runtime wx). Both pixels of
// a 2-aligned pair share (cA,cB), which reproduce the clamped x0/x1 pairs exactly
// (including the x<2 both-columns-0 and x>253 both-columns-63 corner cases).
#define ROWH2(F, r, hA, hB)                       \
  {                                               \
    float fA_ = (F)[(r) * 64 + cA];               \
    float fB_ = (F)[(r) * 64 + cB];               \
    hA = fA_ * (1.f - wxA) + fB_ * wxA;           \
    hB = fA_ * (1.f - wxB) + fB_ * wxB;           \
  }

// ---- fused cal+test features, 256 blocks (one per cal sample) ----
// 2-pixel-wide patches: thread (xg, band) owns x=2xg..2xg+1, rows [32*band, +32)
// (8 quads, rolling 3-row window). Per row: one sy/wy, 2 LDS reads feed 2 x-interps,
// one packed u32 store (calbf/tbf), float2 tres store, one 2-bit gmask read.
// Per-pixel score bits identical to all prior rounds (same expression trees/operands);
// cc accumulation order reassociated (accepted precedent, R6/R8).
// smem map (u32): [0,16256) hist -> CDF -> scatter counters (swizzled); [16256,16272)
// scan wave totals; [16272,16288) cc partials; [16288,17312) thread prefixes; [17312] pos.
__global__ __launch_bounds__(1024, 2) void k_calt(const float* __restrict__ featc,
                                                  const int* __restrict__ gt,
                                                  unsigned short* __restrict__ calbf,
                                                  unsigned short* __restrict__ cdf,
                                                  unsigned short* __restrict__ grouped,
                                                  float* __restrict__ cc,
                                                  const float* __restrict__ featt,
                                                  float* __restrict__ tres,
                                                  unsigned short* __restrict__ tbf) {
  __shared__ unsigned smem[17313];
  __shared__ float sfeat[4096];
  __shared__ __align__(16) unsigned short sstage[STAGE_CAP];
  float* tfeat = (float*)sstage;                    // sstage[0..8191]: dead before phase B
  unsigned* gmask = (unsigned*)(sstage + 8192);     // sstage[8192..12287]: dead before phase B
  const int tid = threadIdx.x;
  const int lane = tid & 63, wv = tid >> 6;
  const int xg = tid & 127, band = tid >> 7;  // 2-px col group / 32-row band
  // per-pixel x-interp params (x = 2xg, 2xg+1): same source expressions as original
  float sxA = 0.25f * (float)(2 * xg) - 0.375f;
  float sxB = 0.25f * (float)(2 * xg + 1) - 0.375f;
  int rawx0 = (int)floorf(sxA);
  float wxA = sxA - (float)rawx0;
  float wxB = sxB - (float)((int)floorf(sxB));  // same floor value as rawx0
  const int cA = rawx0 < 0 ? 0 : rawx0;
  const int cB = rawx0 + 1 > 63 ? 63 : rawx0 + 1;

  const int n = blockIdx.x;
  const int b = n >> 3, sl = n & 7;  // test sample + slice handled by this block
  for (int i = tid; i < HB; i += 1024) smem[i] = 0;
  for (int i = tid; i < 4096; i += 1024) {
    sfeat[i] = featc[n * 4096 + i];
    tfeat[i] = featt[b * 4096 + i];
  }
  // gt bitmask pre-pass: coalesced int4 loads -> 8 KB LDS bitmask
  {
    const int4* gt4 = (const int4*)(gt + (size_t)n * NPIX);
    for (int w = tid; w < 2048; w += 1024) {
      unsigned m = 0;
      #pragma unroll
      for (int j = 0; j < 8; ++j) {
        int4 g = gt4[w * 8 + j];
        m |= (g.x > 0 ? 1u : 0u) << (j * 4);
        m |= (g.y > 0 ? 2u : 0u) << (j * 4);
        m |= (g.z > 0 ? 4u : 0u) << (j * 4);
        m |= (g.w > 0 ? 8u : 0u) << (j * 4);
      }
      gmask[w] = m;
    }
  }
  unsigned short* cbn = calbf + (size_t)n * NPIX;
  __syncthreads();  // S0: feats + hist + gmask ready

  // ---- test slice: quad mt = sl*8+band (rows 4mt..4mt+3) x cols 2xg..2xg+1 ----
  {
    const int mt = sl * 8 + band;
    float tpA, tpB, tcA, tcB, tnA, tnB;
    int rp = (mt == 0) ? 0 : mt - 1;
    int rn = (mt == 63) ? 63 : mt + 1;
    ROWH2(tfeat, rp, tpA, tpB);
    ROWH2(tfeat, mt, tcA, tcB);
    ROWH2(tfeat, rn, tnA, tnB);
    float* resb = tres + (size_t)b * NPIX;
    unsigned short* tbn = tbf + (size_t)b * NPIX;
    #pragma unroll
    for (int j = 0; j < 4; ++j) {
      int y = 4 * mt + j;
      float sy = 0.25f * (float)y - 0.375f;
      int y0i = (int)floorf(sy);
      float wy = sy - (float)y0i;
      float sA = sig_v(j < 2 ? tpA : tcA, j < 2 ? tcA : tnA, wy);
      float sB = sig_v(j < 2 ? tpB : tcB, j < 2 ? tcB : tnB, wy);
      float2 rv = {sA, sB};
      *(float2*)(resb + (y << 8) + 2 * xg) = rv;
      *(unsigned*)(tbn + (y << 8) + 2 * xg) = f2bf_rne(sA) | (f2bf_rne(sB) << 16);
    }
  }

  // ---- cal phase A: 2-wide patch scores, packed stores, bitmask, hist, cc ----
  const int mq0 = band * 8;  // quads mq0..mq0+7 (rows 32*band..+31)
  unsigned long long pm = 0ull;
  float sumsq = 0.f;
  {
    float hpA, hpB, hcA, hcB, hnA, hnB;
    int rp = (mq0 == 0) ? 0 : mq0 - 1;
    ROWH2(sfeat, rp, hpA, hpB);
    ROWH2(sfeat, mq0, hcA, hcB);
    for (int qq = 0; qq < 8; ++qq) {
      int m = mq0 + qq;
      int rn = (m == 63) ? 63 : m + 1;
      ROWH2(sfeat, rn, hnA, hnB);
      #pragma unroll
      for (int j = 0; j < 4; ++j) {
        int y = 4 * m + j;
        float sy = 0.25f * (float)y - 0.375f;
        int y0i = (int)floorf(sy);
        float wy = sy - (float)y0i;
        float sA = sig_v(j < 2 ? hpA : hcA, j < 2 ? hcA : hnA, wy);
        float sB = sig_v(j < 2 ? hpB : hcB, j < 2 ? hcB : hnB, wy);
        unsigned uA = f2bf_rne(sA), uB = f2bf_rne(sB);
        *(unsigned*)(cbn + (y << 8) + 2 * xg) = uA | (uB << 16);
        float rA = __uint_as_float(uA << 16), rB = __uint_as_float(uB << 16);
        sumsq += rA * rA;
        sumsq += rB * rB;
        unsigned bits2 = (gmask[(y << 3) + (xg >> 4)] >> ((2 * xg) & 31)) & 3u;
        if (bits2 & 1u) {
          pm |= 1ull << (qq * 8 + j * 2 + 0);
          atomicAdd(&smem[SW((int)(__float_as_uint(sA) >> 16))], 1u);
        }
        if (bits2 & 2u) {
          pm |= 1ull << (qq * 8 + j * 2 + 1);
          atomicAdd(&smem[SW((int)(__float_as_uint(sB) >> 16))], 1u);
        }
      }
      hpA = hcA; hpB = hcB;
      hcA = hnA; hcB = hnB;
    }
  }
  // cc partials (16 waves); band-patch accumulation order (reassociation accepted)
  #pragma unroll
  for (int off = 32; off; off >>= 1) sumsq += __shfl_xor(sumsq, off);
  if (lane == 0) smem[16272 + wv] = __float_as_uint(sumsq);
  __syncthreads();  // S1: hist + cc partials final
  if (tid == 0) {
    float c = 0.f;
    for (int w = 0; w < 16; ++w) c += __uint_as_float(smem[16272 + w]);
    cc[n] = c;
  }
  // ---- exclusive scan: threads 0..1015, 16 buckets each ----
  const int base = tid * 16;
  unsigned psum = 0;
  if (tid < 1016) {
    #pragma unroll
    for (int j = 0; j < 16; ++j) psum += smem[SW(base + j)];
  }
  unsigned inc = psum;
  #pragma unroll
  for (int off = 1; off < 64; off <<= 1) {
    unsigned v = __shfl_up(inc, off);
    if (lane >= off) inc += v;
  }
  if (lane == 63) smem[16256 + wv] = inc;  // wave totals
  smem[16288 + tid] = inc - psum;          // thread-exclusive prefix within wave
  __syncthreads();  // S2: totals + prefixes ready
  {
    unsigned woff = 0;
    for (int w = 0; w < wv; ++w) woff += smem[16256 + w];  // broadcast reads
    unsigned run = woff + smem[16288 + tid];
    if (tid < 1016) {
      #pragma unroll
      for (int j = 0; j < 16; ++j) {
        int si = SW(base + j);
        unsigned h = smem[si];
        smem[si] = run;  // exclusive CDF -> scatter counters
        run += h;
      }
    }
    if (tid == 1015) smem[17312] = run;  // total positives (lanes above 1015 hold 0)
  }
  __syncthreads();  // S2b: counters final
  // ---- COALESCED u16 cdf copyout ----
  unsigned short* cdfn = cdf + (size_t)n * CDF_STRIDE;
  for (int i = tid; i < HB; i += 1024) cdfn[i] = (unsigned short)smem[SW(i)];
  const unsigned pos = smem[17312];
  if (tid == 0) cdfn[HB] = (unsigned short)pos;  // pos < 2^16 for Bin(65536,1/2) data
  __syncthreads();  // S3: cdf written before counters mutate
  // ---- phase B: patch recompute (bit-exact expression reuse), LDS staging ----
  unsigned short* gn = grouped + (size_t)n * NPIX;
  {
    float hpA, hpB, hcA, hcB, hnA, hnB;
    int rp = (mq0 == 0) ? 0 : mq0 - 1;
    ROWH2(sfeat, rp, hpA, hpB);
    ROWH2(sfeat, mq0, hcA, hcB);
    for (int qq = 0; qq < 8; ++qq) {
      int m = mq0 + qq;
      int rn = (m == 63) ? 63 : m + 1;
      ROWH2(sfeat, rn, hnA, hnB);
      unsigned qb = (unsigned)(pm >> (qq * 8)) & 0xFFu;
      if (qb) {
        #pragma unroll
        for (int j = 0; j < 4; ++j) {
          unsigned pb = (qb >> (j * 2)) & 3u;
          if (pb) {
            int y = 4 * m + j;
            float sy = 0.25f * (float)y - 0.375f;
            int y0i = (int)floorf(sy);
            float wy = sy - (float)y0i;
            if (pb & 1u) {
              float s = sig_v(j < 2 ? hpA : hcA, j < 2 ? hcA : hnA, wy);
              unsigned bits = __float_as_uint(s);
              unsigned idx = atomicAdd(&smem[SW((int)(bits >> 16))], 1u);
              unsigned short lo = (unsigned short)(bits & 0xFFFFu);
              if (idx < STAGE_CAP) sstage[idx] = lo;
              else gn[idx] = lo;  // overflow fallback: same final location
            }
            if (pb & 2u) {
              float s = sig_v(j < 2 ? hpB : hcB, j < 2 ? hcB : hnB, wy);
              unsigned bits = __float_as_uint(s);
              unsigned idx = atomicAdd(&smem[SW((int)(bits >> 16))], 1u);
              unsigned short lo = (unsigned short)(bits & 0xFFFFu);
              if (idx < STAGE_CAP) sstage[idx] = lo;
              else gn[idx] = lo;
            }
          }
        }
      }
      hpA = hcA; hpB = hcB;
      hcA = hnA; hcB = hnB;
    }
  }
  __syncthreads();  // S4: staging complete
  // ---- COALESCED grouped copyout ----
  unsigned lim = pos < STAGE_CAP ? pos : STAGE_CAP;
  for (unsigned i = tid; i < lim; i += 1024) gn[i] = sstage[i];
}

// ---- merged GEMM + cdf transpose; grid (8, 80): y<64 GEMM, y>=64 transpose ----
// GEMM: gpart[ks][nt][m*32+nl] = <test_m, cal_(nt*32+nl)>, LDS-staged, XOR-swizzled,
// 32x32x16 bf16 MFMA, wave = K-quarter split, cross-wave reduce in lred.
// Transpose: 128 blocks, ONE 128-bucket tile each (R8's 8-block version serialized the
// latency-bound uncoalesced read side 16x -> +65 us; R9's 128-block version measured
// best — keep). cdfT[bucket][n] = cdf[n][bucket], bit-exact search input.
__global__ __launch_bounds__(256) void k_gemmtr(const unsigned short* __restrict__ tbf,
                                                const unsigned short* __restrict__ cbf,
                                                float* __restrict__ gpart,
                                                const unsigned short* __restrict__ cdf,
                                                unsigned short* __restrict__ cdfT) {
  __shared__ __align__(16) char lds[81920];
  const int tid = threadIdx.x;
  if (blockIdx.y >= 64) {
    // ---- transpose role: tile t = (y-64)*8 + x in [0,127) ----
    const int t = (blockIdx.y - 64) * 8 + blockIdx.x;
    if (t >= 127) return;
    unsigned short (*tile)[136] = (unsigned short (*)[136])lds;  // 16B-aligned rows
    const int b0 = t * 128;
    const unsigned short* src = cdf + (size_t)tid * CDF_STRIDE + b0;
    #pragma unroll
    for (int j = 0; j < 128; j += 8)
      *(int4*)&tile[tid][j] = *(const int4*)(src + j);
    __syncthreads();
    for (int j = 0; j < 128; ++j)
      cdfT[(size_t)(b0 + j) * 256 + tid] = tile[tid][j];
    return;
  }
  // ---- GEMM role ----
  unsigned short* As = (unsigned short*)lds;            // 32 KB
  unsigned short* Bs = (unsigned short*)(lds + 32768);  // 32 KB
  float (*lred)[1024] = (float (*)[1024])(lds + 65536); // 16 KB
  const int lane = tid & 63, wv = tid >> 6;
  const int r = lane & 31, half = lane >> 5;
  const int nt = blockIdx.x;              // 0..7: cal column tile
  f32x16 acc;
  #pragma unroll
  for (int i = 0; i < 16; ++i) acc[i] = 0.f;
  for (int ch = 0; ch < 2; ++ch) {        // two 512-K chunks of this block's 1024-K slice
    const size_t kbase = (size_t)blockIdx.y * 1024 + ch * 512;
    __syncthreads();
    #pragma unroll
    for (int s = 0; s < 16; ++s) {
      int flat = s * 256 + tid;           // 0..4095; <2048 = A, else B (wave-uniform per s)
      int rem = flat & 2047;
      int row = rem >> 6, kb = rem & 63;
      const unsigned short* src = (flat >= 2048)
          ? cbf + (size_t)(nt * 32 + row) * NPIX + kbase + kb * 8
          : tbf + (size_t)row * NPIX + kbase + kb * 8;
      int slot = ((kb << 5) + row) ^ (kb & 31);   // XOR swizzle breaks write-bank collisions
      int4 v = *(const int4*)src;
      *(int4*)((flat >= 2048 ? Bs : As) + slot * 8) = v;
    }
    __syncthreads();
    #pragma unroll
    for (int i = 0; i < 8; ++i) {         // wave's K-quarter: kblk in [wv*16, wv*16+16)
      int k8 = (wv << 4) + i * 2 + half;
      int slot = ((k8 << 5) + r) ^ (k8 & 31);
      bf16x8 a = *(const bf16x8*)(As + slot * 8);
      bf16x8 b = *(const bf16x8*)(Bs + slot * 8);
      acc = __builtin_amdgcn_mfma_f32_32x32x16_bf16(a, b, acc, 0, 0, 0);
    }
  }
  // C/D layout (HW-verified): col = lane&31, row = (reg&3) + 8*(reg>>2) + 4*(lane>>5)
  #pragma unroll
  for (int rg = 0; rg < 16; ++rg) {
    int m = (rg & 3) + 8 * (rg >> 2) + 4 * half;
    lred[wv][m * 32 + r] = acc[rg];
  }
  __syncthreads();
  float* gp = gpart + (size_t)(blockIdx.y * 8 + nt) * 1024;
  for (int e = tid; e < 1024; e += 256)
    gp[e] = lred[0][e] + lred[1][e] + lred[2][e] + lred[3][e];
}

// ---- tt + weights + weighted-quantile; zero-inits facc; writes thr/lam ----
__global__ __launch_bounds__(512) void k_quantw(const float* __restrict__ gpart,
                                                const float* __restrict__ cc,
                                                const unsigned short* __restrict__ tbf,
                                                const unsigned short* __restrict__ cdf,
                                                const unsigned short* __restrict__ cdfT,
                                                const unsigned short* __restrict__ grouped,
                                                float* __restrict__ lam,
                                                float* __restrict__ thr,
                                                int* __restrict__ facc) {
  __shared__ float qs[256];
  __shared__ float bins[4096];
  __shared__ float red[8];
  __shared__ float tpart[16];
  __shared__ float bc[3];      // [0]=wsum [1]=S(mid) [2]=tt
  __shared__ unsigned sBin;
  const int b = blockIdx.x, tid = threadIdx.x;
  const int lane = tid & 63, wv = tid >> 6;

  if (tid < 4) facc[b * 4 + tid] = 0;
  for (int i = tid; i < 4096; i += 512) bins[i] = 0.f;
  if (tid == 0) sBin = 0xFFFFFFFFu;

  // ---- tt[b]: bit-exact virtual-thread replica of the original 1024-thread reduction ----
  {
    const unsigned short* tbn = tbf + (size_t)b * NPIX;
    const int xa = tid & 255, ya = tid >> 8;        // virtual thread vt = tid
    const int yb = ya + 2;                          // virtual thread vt = tid + 512
    float sa = 0.f, sb = 0.f;
    #pragma unroll 4
    for (int it = 0; it < 64; ++it) {
      float ra = __uint_as_float((unsigned)tbn[((it * 4 + ya) << 8) + xa] << 16);
      float rb = __uint_as_float((unsigned)tbn[((it * 4 + yb) << 8) + xa] << 16);
      sa += ra * ra;
      sb += rb * rb;
    }
    #pragma unroll
    for (int off = 32; off; off >>= 1) {
      sa += __shfl_xor(sa, off);
      sb += __shfl_xor(sb, off);
    }
    if (lane == 0) { tpart[wv] = sa; tpart[8 + wv] = sb; }
  }
  __syncthreads();
  if (tid == 0) {
    float t = 0.f;
    for (int w = 0; w < 16; ++w) t += tpart[w];
    bc[2] = t;
  }
  // ---- weights g-sum (independent of tt) ----
  float g = 0.f;
  if (tid < 256) {
    const float* gp = gpart + ((tid >> 5) * 1024) + (b * 32) + (tid & 31);
    #pragma unroll 8
    for (int ks = 0; ks < 64; ++ks) g += gp[(size_t)ks * 8192];
  }
  __syncthreads();  // bc[2] visible
  float k = 0.f;
  if (tid < 256) {
    float d2 = bc[2] + cc[tid] - 2.f * g;
    k = expf(-d2 * (1.f / 8192.f));
  }
  float v = k;
  #pragma unroll
  for (int off = 32; off; off >>= 1) v += __shfl_xor(v, off);
  if (lane == 0) red[wv] = v;
  __syncthreads();
  if (tid == 0) {
    float ws = 1.f;
    for (int w = 0; w < 8; ++w) ws += red[w];
    bc[0] = ws;
  }
  __syncthreads();
  const float wsum = bc[0];
  const float wlast = 1.f / wsum;
  const float R = ALPHA - wlast;
  if (R <= 0.f) {  // risk >= alpha for every lam -> low -> 1.0f, thr 0 (predict all)
    if (tid == 0) { lam[b] = 1.0f; thr[b] = 0.0f; }
    return;
  }
  if (tid < 256) {
    unsigned pos = cdf[(size_t)tid * CDF_STRIDE + HB];
    qs[tid] = k / (wsum * (float)(pos ? pos : 1u));
  }
  __syncthreads();

  // ---- 14-step binary search over hi-16 buckets (coalesced via cdfT) ----
  int lo = 0, hi = HB;
  float baseS = 0.f;
  for (int it = 0; it < 14; ++it) {
    int mid = (lo + hi) >> 1;
    float p = 0.f;
    if (tid < 256) p = qs[tid] * (float)cdfT[(size_t)mid * 256 + tid];
    float r = p;
    #pragma unroll
    for (int off = 32; off; off >>= 1) r += __shfl_xor(r, off);
    if (lane == 0) red[wv] = r;
    __syncthreads();
    if (tid == 0) {
      float s = 0.f;
      for (int w = 0; w < 8; ++w) s += red[w];
      bc[1] = s;
    }
    __syncthreads();
    float S = bc[1];
    if (S < R) { lo = mid; baseS = S; } else { hi = mid; }
  }
  const int B = lo;  // crossing bucket; baseS = weighted count below it

  // ---- gather bucket B members into 4096-bin weighted histogram of lo16>>4 ----
  {
    const int n = tid >> 1;
    const float q = qs[n];
    const unsigned short* cn = cdf + (size_t)n * CDF_STRIDE;
    const unsigned short* gn = grouped + (size_t)n * NPIX;
    unsigned e0 = cn[B + 1];
    for (unsigned j = (unsigned)cn[B] + (tid & 1); j < e0; j += 2)
      atomicAdd(&bins[gn[j] >> 4], q);
  }
  __syncthreads();

  // ---- wave 0: scan 4096 bins, find crossing bin ----
  if (wv == 0) {
    float s = 0.f;
    for (int j = 0; j < 64; ++j) s += bins[lane * 64 + j];
    float inc = s;
    #pragma unroll
    for (int off = 1; off < 64; off <<= 1) {
      float u = __shfl_up(inc, off);
      if (lane >= off) inc += u;
    }
    float pre = inc - s;
    bool hit = (baseS + pre < R) && (baseS + inc >= R);
    unsigned long long m = __ballot(hit);
    int ow = m ? (__ffsll((unsigned long long)m) - 1) : -1;
    if (lane == ow) {
      float run = baseS + pre;
      unsigned bin = (unsigned)lane * 64 + 63;
      for (int j = 0; j < 64; ++j) {
        float bv = bins[lane * 64 + j];
        if (run + bv >= R) { bin = (unsigned)lane * 64 + j; break; }
        run += bv;
      }
      sBin = bin;
    }
    if (m == 0 && lane == 0) sBin = 4095u;  // f32-rounding fallback (unreachable in practice)
  }
  __syncthreads();
  if (tid == 0) {
    unsigned tb = ((unsigned)B << 16) | (sBin << 4);
    lam[b] = 1.0f - __uint_as_float(tb | 0x8u);     // mid-bin representative
    thr[b] = __uint_as_float((tb | 0xFu) + 1u);     // strictly above bin top: pred = res > u*
  }
}

// ---- final partials + output: grid (32 samples, 8 segments) ----
// Absorbs k_out: the 8th-arriving segment block per sample reads the device-scope
// accumulated counts and writes out[] directly (saves a launch).
__global__ __launch_bounds__(256) void k_finalp(const float* __restrict__ tres,
                                                const int* __restrict__ tgt,
                                                const float* __restrict__ thr,
                                                const float* __restrict__ lam,
                                                int* __restrict__ facc,
                                                float* __restrict__ out) {
  __shared__ int red[12];
  const int b = blockIdx.x, seg = blockIdx.y, tid = threadIdx.x;
  const int lane = tid & 63, wv = tid >> 6;
  const float th = thr[b];
  const float4* rb4 = (const float4*)(tres + (size_t)b * NPIX + seg * 8192);
  const int4* gb4 = (const int4*)(tgt + (size_t)b * NPIX + seg * 8192);
  int sz = 0, tp = 0, tpos = 0;
  #pragma unroll
  for (int i = 0; i < 8; ++i) {
    float4 r4 = rb4[i * 256 + tid];
    int4 g4 = gb4[i * 256 + tid];
    int p0 = (r4.x >= th), t0 = (g4.x > 0);
    int p1 = (r4.y >= th), t1 = (g4.y > 0);
    int p2 = (r4.z >= th), t2 = (g4.z > 0);
    int p3 = (r4.w >= th), t3 = (g4.w > 0);
    sz += p0 + p1 + p2 + p3;
    tp += (p0 & t0) + (p1 & t1) + (p2 & t2) + (p3 & t3);
    tpos += t0 + t1 + t2 + t3;
  }
  #pragma unroll
  for (int off = 32; off; off >>= 1) {
    sz += __shfl_xor(sz, off);
    tp += __shfl_xor(tp, off);
    tpos += __shfl_xor(tpos, off);
  }
  if (lane == 0) { red[wv] = sz; red[4 + wv] = tp; red[8 + wv] = tpos; }
  __syncthreads();
  if (tid == 0) {
    int s0 = red[0] + red[1] + red[2] + red[3];
    int s1 = red[4] + red[5] + red[6] + red[7];
    int s2 = red[8] + red[9] + red[10] + red[11];
    atomicAdd(&facc[b * 4 + 0], s0);
    atomicAdd(&facc[b * 4 + 1], s1);
    atomicAdd(&facc[b * 4 + 2], s2);
    __threadfence();  // publish before arrival
    int done = atomicAdd(&facc[b * 4 + 3], 1);
    if (done == 7) {  // last of 8 segment blocks: all adds are visible via atomics
      int f0 = atomicAdd(&facc[b * 4 + 0], 0);
      int f1 = atomicAdd(&facc[b * 4 + 1], 0);
      int f2 = atomicAdd(&facc[b * 4 + 2], 0);
      float tposf = (float)(f2 > 0 ? f2 : 1);
      out[b] = 1.f - (float)f1 / tposf;   // fnr_test
      out[32 + b] = lam[b];               // lambda
      out[64 + b] = (float)f0;            // size
    }
  }
}

extern "C" void kernel_launch(void* const* d_in, const int* in_sizes, int n_in,
                              void* d_out, int out_size, void* d_ws, size_t ws_size,
                              hipStream_t stream) {
  const float* cal_feat = (const float*)d_in[0];
  const float* test_feat = (const float*)d_in[1];
  const int* cal_gt = (const int*)d_in[2];
  const int* test_gt = (const int*)d_in[3];
  float* out = (float*)d_out;
  char* ws = (char*)d_ws;

  float* test_res = (float*)(ws + OFF_TESTRES);
  unsigned short* cal_bf = (unsigned short*)(ws + OFF_CALBF);
  unsigned short* test_bf = (unsigned short*)(ws + OFF_TESTBF);
  unsigned short* grouped = (unsigned short*)(ws + OFF_GROUPED);
  unsigned short* cdf = (unsigned short*)(ws + OFF_CDF);
  unsigned short* cdfT = (unsigned short*)(ws + OFF_CDFT);
  float* gpart = (float*)(ws + OFF_GPART);
  float* cc = (float*)(ws + OFF_CC);
  float* thr = (float*)(ws + OFF_THR);
  float* lam = (float*)(ws + OFF_LAM);
  int* facc = (int*)(ws + OFF_FACC);

  k_calt<<<dim3(256), dim3(1024), 0, stream>>>(cal_feat, cal_gt, cal_bf, cdf, grouped, cc,
                                               test_feat, test_res, test_bf);
  k_gemmtr<<<dim3(8, 80), dim3(256), 0, stream>>>(test_bf, cal_bf, gpart, cdf, cdfT);
  k_quantw<<<dim3(32), dim3(512), 0, stream>>>(gpart, cc, test_bf, cdf, cdfT, grouped,
                                               lam, thr, facc);
  k_finalp<<<dim3(32, 8), dim3(256), 0, stream>>>(test_res, test_gt, thr, lam, facc, out);
}